// Round 3
// baseline (4929.045 us; speedup 1.0000x reference)
//
#include <hip/hip_runtime.h>
#include <stdint.h>

#define B_ROWS 2048
#define DIM    2048
#define FDICT  32768
#define KSEL   64
#define TOPC   128     // candidate list; refined bit-exactly vs np.einsum fp32
#define FCHUNK 8192
#define NCHUNK (FDICT / FCHUNK)

// ======================= encode GEMM (fp32, vector ALU) =======================
// Candidate generation only: values are re-derived bit-exactly in refine_np.
#define BM 128
#define BN 128
#define BK 32
#define LDS_A (BM + 4)

__global__ __launch_bounds__(256) void enc_gemm_kernel(
    const float* __restrict__ x,
    const float* __restrict__ Wenc,
    const float* __restrict__ benc,
    float* __restrict__ mu,
    int chunk_base)
{
    __shared__ __align__(16) float As[BK][LDS_A];
    __shared__ __align__(16) float Bs[BK][LDS_A];
    const int tid = threadIdx.x;
    const int tx  = tid & 15;
    const int ty  = tid >> 4;
    const int row0 = blockIdx.y * BM;
    const int col0 = blockIdx.x * BN;

    float acc[8][8];
#pragma unroll
    for (int i = 0; i < 8; ++i)
#pragma unroll
        for (int j = 0; j < 8; ++j) acc[i][j] = 0.f;

    const float* aptr = x    + (size_t)row0 * DIM;
    const float* bptr = Wenc + (size_t)(chunk_base + col0) * DIM;

    for (int k0 = 0; k0 < DIM; k0 += BK) {
#pragma unroll
        for (int s = 0; s < 4; ++s) {
            int q  = tid + 256 * s;
            int r  = q >> 3;
            int kq = (q & 7) << 2;
            float4 va = *(const float4*)(aptr + (size_t)r * DIM + k0 + kq);
            As[kq + 0][r] = va.x;
            As[kq + 1][r] = va.y;
            As[kq + 2][r] = va.z;
            As[kq + 3][r] = va.w;
            float4 vb = *(const float4*)(bptr + (size_t)r * DIM + k0 + kq);
            Bs[kq + 0][r] = vb.x;
            Bs[kq + 1][r] = vb.y;
            Bs[kq + 2][r] = vb.z;
            Bs[kq + 3][r] = vb.w;
        }
        __syncthreads();
#pragma unroll 8
        for (int kk = 0; kk < BK; ++kk) {
            float a[8], b[8];
            *(float4*)&a[0] = *(const float4*)&As[kk][ty * 8 + 0];
            *(float4*)&a[4] = *(const float4*)&As[kk][ty * 8 + 4];
            *(float4*)&b[0] = *(const float4*)&Bs[kk][tx * 8 + 0];
            *(float4*)&b[4] = *(const float4*)&Bs[kk][tx * 8 + 4];
#pragma unroll
            for (int i = 0; i < 8; ++i)
#pragma unroll
                for (int j = 0; j < 8; ++j)
                    acc[i][j] = fmaf(a[i], b[j], acc[i][j]);
        }
        __syncthreads();
    }

    float be[8];
#pragma unroll
    for (int j = 0; j < 8; ++j)
        be[j] = benc[chunk_base + col0 + tx * 8 + j];
#pragma unroll
    for (int i = 0; i < 8; ++i) {
        float4 o0, o1;
        o0.x = acc[i][0] + be[0]; o0.y = acc[i][1] + be[1];
        o0.z = acc[i][2] + be[2]; o0.w = acc[i][3] + be[3];
        o1.x = acc[i][4] + be[4]; o1.y = acc[i][5] + be[5];
        o1.z = acc[i][6] + be[6]; o1.w = acc[i][7] + be[7];
        float* orow = mu + (size_t)(row0 + ty * 8 + i) * FCHUNK + col0 + tx * 8;
        *(float4*)(orow + 0) = o0;
        *(float4*)(orow + 4) = o1;
    }
}

// ======================= running top-TOPC merge (exact radix select) ==========
#define EQCAP 128

__global__ __launch_bounds__(256) void topk_merge_kernel(
    const float* __restrict__ mu,
    float* __restrict__ run_val,
    int* __restrict__ run_idx,
    int chunk_base)
{
    const int row = blockIdx.x;
    const int tid = threadIdx.x;
    const int NTOT = FCHUNK + TOPC;

    __shared__ uint32_t uabs[FCHUNK + TOPC];
    __shared__ float oldv[TOPC];
    __shared__ int   oldi[TOPC];
    __shared__ int   hist[256];
    __shared__ uint32_t sh_prefix;
    __shared__ int   sh_cgt;
    __shared__ int   cnt_out, cnt_eq;
    __shared__ float newv[TOPC];
    __shared__ int   newi[TOPC];
    __shared__ int   eq_j[EQCAP];

    const float* murow = mu + (size_t)row * FCHUNK;

    for (int j = tid; j < FCHUNK; j += 256)
        uabs[j] = __float_as_uint(murow[j]) & 0x7fffffffu;
    if (tid < TOPC) {
        float v = run_val[row * TOPC + tid];
        int   g = run_idx[row * TOPC + tid];
        oldv[tid] = v; oldi[tid] = g;
        uabs[FCHUNK + tid] = (g >= 0) ? (__float_as_uint(v) & 0x7fffffffu) : 0u;
    }
    if (tid == 0) { sh_prefix = 0u; sh_cgt = 0; cnt_out = 0; cnt_eq = 0; }
    __syncthreads();

    for (int p = 3; p >= 0; --p) {
        hist[tid] = 0;
        __syncthreads();
        const uint32_t mask = (p == 3) ? 0u : (0xffffffffu << ((p + 1) * 8));
        const uint32_t pref = sh_prefix;
        for (int j = tid; j < NTOT; j += 256) {
            uint32_t u = uabs[j];
            if ((u & mask) == pref)
                atomicAdd(&hist[(u >> (p * 8)) & 255], 1);
        }
        __syncthreads();
        if (tid == 0) {
            int cum = sh_cgt;
            int chosen = 0;
            for (int b = 255; b >= 0; --b) {
                int c = hist[b];
                if (cum + c >= TOPC) { chosen = b; break; }
                cum += c;
            }
            sh_prefix = sh_prefix | ((uint32_t)chosen << (p * 8));
            sh_cgt = cum;
        }
        __syncthreads();
    }

    const uint32_t uth = sh_prefix;
    for (int j = tid; j < NTOT; j += 256) {
        uint32_t u = uabs[j];
        if (u > uth) {
            int pos = atomicAdd(&cnt_out, 1);
            if (j < FCHUNK) { newv[pos] = murow[j];          newi[pos] = chunk_base + j; }
            else            { newv[pos] = oldv[j - FCHUNK];  newi[pos] = oldi[j - FCHUNK]; }
        } else if (u == uth) {
            int e = atomicAdd(&cnt_eq, 1);
            if (e < EQCAP) eq_j[e] = j;
        }
    }
    __syncthreads();
    if (tid == 0) {
        int ne = cnt_eq < EQCAP ? cnt_eq : EQCAP;
        int need = TOPC - cnt_out;
        for (int s = 0; s < need; ++s) {
            int best = -1; long bestg = 0x7fffffffL;
            for (int t = 0; t < ne; ++t) {
                int j = eq_j[t];
                if (j < 0) continue;
                long g = (j < FCHUNK) ? (long)(chunk_base + j) : (long)oldi[j - FCHUNK];
                if (g < 0) g = 0x7ffffffeL;
                if (g < bestg) { bestg = g; best = t; }
            }
            if (best < 0) break;
            int j = eq_j[best]; eq_j[best] = -1;
            int pos = cnt_out + s;
            if (j < FCHUNK) { newv[pos] = murow[j];          newi[pos] = chunk_base + j; }
            else            { newv[pos] = oldv[j - FCHUNK];  newi[pos] = oldi[j - FCHUNK]; }
        }
    }
    __syncthreads();
    if (tid < TOPC) {
        run_val[row * TOPC + tid] = newv[tid];
        run_idx[row * TOPC + tid] = newi[tid];
    }
}

// ============ np.einsum-bit-exact refinement of TOPC candidates ==============
// Replicates numpy's fp32 SSE sum-of-products: 4 accumulators over d%4
// (ascending d, round(mul) then round(add), NO fma), combined as
// (a0+a2)+(a1+a3), then + b_enc. Rank by fp32 bit pattern of |v|, ties by
// lowest feature index (stable top_k). This matches the np reference values
// bit-for-bit, so selection flips vanish.
#define RGROUP 8
#define NROUND (TOPC / RGROUP)

__global__ __launch_bounds__(256) void refine_np_kernel(
    const float* __restrict__ x,
    const float* __restrict__ Wenc,
    const float* __restrict__ benc,
    const int* __restrict__ run_idx,
    float* __restrict__ sel_val,
    int* __restrict__ sel_idx)
{
    const int row  = blockIdx.x;
    const int tid  = threadIdx.x;
    const int wave = tid >> 6;
    const int lane = tid & 63;

    __shared__ __align__(16) float  xs[DIM];
    __shared__ __align__(16) float4 wslab4[RGROUP * (DIM / 4)];
    __shared__ float cval[TOPC];
    __shared__ int   cidx[TOPC];
    __shared__ float accs[RGROUP][4];

    {
        const float4* xr = (const float4*)(x + (size_t)row * DIM);
        for (int i = tid; i < DIM / 4; i += 256)
            ((float4*)xs)[i] = xr[i];
    }
    if (tid < TOPC) cidx[tid] = run_idx[row * TOPC + tid];
    __syncthreads();

    const float* wsl = (const float*)wslab4;

    for (int r = 0; r < NROUND; ++r) {
        const int c0 = r * RGROUP;
#pragma unroll
        for (int rr = 0; rr < RGROUP; ++rr) {
            int f = cidx[c0 + rr];
            if (f >= 0) {
                const float4* wr = (const float4*)(Wenc + (size_t)f * DIM);
                wslab4[rr * (DIM / 4) + tid]       = wr[tid];
                wslab4[rr * (DIM / 4) + 256 + tid] = wr[256 + tid];
            }
        }
        __syncthreads();
        // wave w computes candidates {2w, 2w+1}; lanes 0..7: (cand, accum j)
        if (lane < 8) {
            int cl = wave * 2 + (lane >> 2);
            int j  = lane & 3;
            int f  = cidx[c0 + cl];
            float a = 0.f;
            if (f >= 0) {
                const float* wrow = wsl + cl * DIM;
#pragma unroll 8
                for (int t = 0; t < DIM / 4; ++t) {
                    int d = (t << 2) | j;
                    a = __fadd_rn(a, __fmul_rn(xs[d], wrow[d]));
                }
            }
            accs[cl][j] = a;
        }
        __syncthreads();
        if (tid < RGROUP) {
            int f = cidx[c0 + tid];
            float v = __fadd_rn(__fadd_rn(accs[tid][0], accs[tid][2]),
                                __fadd_rn(accs[tid][1], accs[tid][3]));
            cval[c0 + tid] = (f >= 0) ? __fadd_rn(v, benc[f]) : 0.f;
        }
        __syncthreads();
    }

    if (tid < TOPC) {
        int f = cidx[tid];
        if (f >= 0) {
            uint32_t av = __float_as_uint(cval[tid]) & 0x7fffffffu;
            int rank = 0;
            for (int u = 0; u < TOPC; ++u) {
                if (u == tid) continue;
                int fu = cidx[u];
                if (fu < 0) continue;
                uint32_t au = __float_as_uint(cval[u]) & 0x7fffffffu;
                if (au > av || (au == av && fu < f)) ++rank;
            }
            if (rank < KSEL) {
                sel_val[row * KSEL + rank] = cval[tid];
                sel_idx[row * KSEL + rank] = f;
            }
        }
    }
}

// ======================= decode =======================
__global__ __launch_bounds__(256) void transpose_kernel(
    const float* __restrict__ Wdec,   // [DIM][FDICT]
    float* __restrict__ Wt,           // [FCHUNK][DIM]
    int chunk_base)
{
    __shared__ float t[32][33];
    const int j0 = blockIdx.x * 32;
    const int d0 = blockIdx.y * 32;
    const int tx = threadIdx.x & 31;
    const int ty = threadIdx.x >> 5;
#pragma unroll
    for (int r = 0; r < 4; ++r)
        t[ty + 8 * r][tx] = Wdec[(size_t)(d0 + ty + 8 * r) * FDICT + chunk_base + j0 + tx];
    __syncthreads();
#pragma unroll
    for (int r = 0; r < 4; ++r)
        Wt[(size_t)(j0 + ty + 8 * r) * DIM + d0 + tx] = t[tx][ty + 8 * r];
}

__global__ __launch_bounds__(256) void init_out_kernel(
    float* __restrict__ out, const float* __restrict__ bdec)
{
    int i = blockIdx.x * 256 + threadIdx.x;
    out[i] = bdec[i & (DIM - 1)];
}

__global__ __launch_bounds__(256) void init_topk_kernel(
    float* __restrict__ run_val, int* __restrict__ run_idx)
{
    int i = blockIdx.x * 256 + threadIdx.x;
    if (i < B_ROWS * TOPC) { run_val[i] = 0.f; run_idx[i] = -1; }
}

__global__ __launch_bounds__(256) void decode_kernel(
    const float* __restrict__ Wt,       // [FCHUNK][DIM] transposed chunk
    const float* __restrict__ sel_val,
    const int* __restrict__ sel_idx,
    float* __restrict__ out,
    int chunk_base)
{
    const int row = blockIdx.x;
    const int tid = threadIdx.x;
    __shared__ float vv[KSEL];
    __shared__ int   ff[KSEL];
    if (tid < KSEL) {
        vv[tid] = sel_val[row * KSEL + tid];
        ff[tid] = sel_idx[row * KSEL + tid] - chunk_base;
    }
    __syncthreads();
    float acc[8] = {0.f, 0.f, 0.f, 0.f, 0.f, 0.f, 0.f, 0.f};
    for (int k = 0; k < KSEL; ++k) {
        int f = ff[k];
        if (0 <= f && f < FCHUNK) {
            float v = vv[k];
            const float* wrow = Wt + (size_t)f * DIM;
#pragma unroll
            for (int i = 0; i < 8; ++i)
                acc[i] += v * wrow[tid + 256 * i];
        }
    }
    float* orow = out + (size_t)row * DIM;
#pragma unroll
    for (int i = 0; i < 8; ++i)
        orow[tid + 256 * i] += acc[i];
}

// ======================= launch =======================
extern "C" void kernel_launch(void* const* d_in, const int* in_sizes, int n_in,
                              void* d_out, int out_size, void* d_ws, size_t ws_size,
                              hipStream_t stream)
{
    const float* x    = (const float*)d_in[0];
    const float* Wenc = (const float*)d_in[1];
    const float* benc = (const float*)d_in[2];
    const float* Wdec = (const float*)d_in[3];
    const float* bdec = (const float*)d_in[4];
    (void)in_sizes; (void)n_in; (void)out_size; (void)ws_size;
    float* out = (float*)d_out;

    char* ws = (char*)d_ws;
    size_t off = 0;
    float* buf0    = (float*)(ws + off); off += (size_t)B_ROWS * FCHUNK * 4;  // 64 MB
    float* run_val = (float*)(ws + off); off += (size_t)B_ROWS * TOPC * 4;
    int*   run_idx = (int*)  (ws + off); off += (size_t)B_ROWS * TOPC * 4;
    float* sel_val = (float*)(ws + off); off += (size_t)B_ROWS * KSEL * 4;
    int*   sel_idx = (int*)  (ws + off); off += (size_t)B_ROWS * KSEL * 4;

    init_topk_kernel<<<(B_ROWS * TOPC + 255) / 256, 256, 0, stream>>>(run_val, run_idx);
    for (int c = 0; c < NCHUNK; ++c) {
        enc_gemm_kernel<<<dim3(FCHUNK / BN, B_ROWS / BM), 256, 0, stream>>>(
            x, Wenc, benc, buf0, c * FCHUNK);
        topk_merge_kernel<<<B_ROWS, 256, 0, stream>>>(buf0, run_val, run_idx, c * FCHUNK);
    }
    refine_np_kernel<<<B_ROWS, 256, 0, stream>>>(x, Wenc, benc, run_idx, sel_val, sel_idx);
    init_out_kernel<<<(B_ROWS * DIM) / 256, 256, 0, stream>>>(out, bdec);
    for (int c = 0; c < NCHUNK; ++c) {
        transpose_kernel<<<dim3(FCHUNK / 32, DIM / 32), 256, 0, stream>>>(
            Wdec, buf0, c * FCHUNK);
        decode_kernel<<<B_ROWS, 256, 0, stream>>>(buf0, sel_val, sel_idx, out, c * FCHUNK);
    }
}

// Round 4
// 2239.936 us; speedup vs baseline: 2.2005x; 2.2005x over previous
//
#include <hip/hip_runtime.h>
#include <stdint.h>

#define B_ROWS 2048
#define DIM    2048
#define FDICT  32768
#define KSEL   64
#define TOPC   128     // candidate list; refined bit-exactly vs np.einsum fp32
#define FCHUNK 8192
#define NCHUNK (FDICT / FCHUNK)

typedef __attribute__((ext_vector_type(8))) short bf16x8;
typedef __attribute__((ext_vector_type(4))) float f32x4;

// =================== encode GEMM (bf16 MFMA, candidate generation) ===========
// mu_approx[b, j] = dot(bf16(x[b,:]), bf16(Wenc[j,:])) + benc[j], fp32 accum.
// Only used to pick TOPC candidates per row; refine_np re-derives exact values.
#define TM 128
#define TN 128
#define TK 32
#define LSTRIDE 40   // 32 k-elems + 8 pad (80B row stride: breaks bank conflicts)

__device__ __forceinline__ void load8(float* d, const float* base, int r, int k)
{
    const float4* p = (const float4*)(base + (size_t)r * DIM + k);
    float4 u = p[0], v = p[1];
    d[0] = u.x; d[1] = u.y; d[2] = u.z; d[3] = u.w;
    d[4] = v.x; d[5] = v.y; d[6] = v.z; d[7] = v.w;
}

__device__ __forceinline__ void cvt_store16(short* dst, const float* v)
{
    union { short s[8]; bf16x8 w; } u;
#pragma unroll
    for (int j = 0; j < 8; ++j) {
        union { __bf16 h; short s; } cv;
        cv.h = (__bf16)v[j];            // RNE; compiler pairs into v_cvt_pk_bf16_f32
        u.s[j] = cv.s;
    }
    *(bf16x8*)dst = u.w;
}

__global__ __launch_bounds__(256) void enc_gemm_mfma(
    const float* __restrict__ x,
    const float* __restrict__ Wenc,
    const float* __restrict__ benc,
    float* __restrict__ mu,
    int chunk_base)
{
    __shared__ __align__(16) short As[TM * LSTRIDE];
    __shared__ __align__(16) short Bs[TM * LSTRIDE];

    const int tid  = threadIdx.x;
    const int lane = tid & 63;
    const int wv   = tid >> 6;
    const int wr   = wv >> 1, wc = wv & 1;   // wave grid 2x2, each wave 64x64
    const int lr   = lane & 15, lg = lane >> 4;
    const int row0 = blockIdx.y * TM;
    const int col0 = blockIdx.x * TN;

    // staging: 512 segments of 8 floats; thread t handles segs t and t+256
    const int s0 = tid, s1 = tid + 256;
    const int r0 = s0 >> 2, k0q0 = (s0 & 3) * 8;
    const int r1 = s1 >> 2, k0q1 = (s1 & 3) * 8;

    const float* aBase = x    + (size_t)row0 * DIM;
    const float* bBase = Wenc + (size_t)(chunk_base + col0) * DIM;

    f32x4 acc[4][4] = {};

    float a0[8], a1[8], b0[8], b1[8];
    load8(a0, aBase, r0, k0q0);
    load8(a1, aBase, r1, k0q1);
    load8(b0, bBase, r0, k0q0);
    load8(b1, bBase, r1, k0q1);

    for (int ks = 0; ks < DIM / TK; ++ks) {
        __syncthreads();                      // previous compute done with LDS
        cvt_store16(As + r0 * LSTRIDE + k0q0, a0);
        cvt_store16(As + r1 * LSTRIDE + k0q1, a1);
        cvt_store16(Bs + r0 * LSTRIDE + k0q0, b0);
        cvt_store16(Bs + r1 * LSTRIDE + k0q1, b1);
        if (ks + 1 < DIM / TK) {              // prefetch next tile under MFMA
            const int kn = (ks + 1) * TK;
            load8(a0, aBase, r0, kn + k0q0);
            load8(a1, aBase, r1, kn + k0q1);
            load8(b0, bBase, r0, kn + k0q0);
            load8(b1, bBase, r1, kn + k0q1);
        }
        __syncthreads();                      // LDS writes visible

        bf16x8 af[4], bfr[4];
#pragma unroll
        for (int mi = 0; mi < 4; ++mi)
            af[mi] = *(const bf16x8*)(As + (wr * 64 + mi * 16 + lr) * LSTRIDE + lg * 8);
#pragma unroll
        for (int ni = 0; ni < 4; ++ni)
            bfr[ni] = *(const bf16x8*)(Bs + (wc * 64 + ni * 16 + lr) * LSTRIDE + lg * 8);
#pragma unroll
        for (int mi = 0; mi < 4; ++mi)
#pragma unroll
            for (int ni = 0; ni < 4; ++ni)
                acc[mi][ni] = __builtin_amdgcn_mfma_f32_16x16x32_bf16(
                    af[mi], bfr[ni], acc[mi][ni], 0, 0, 0);
    }

    float bias[4];
#pragma unroll
    for (int ni = 0; ni < 4; ++ni)
        bias[ni] = benc[chunk_base + col0 + wc * 64 + ni * 16 + lr];
    // C/D layout (m89-verified): col = lane&15, row = (lane>>4)*4 + reg
#pragma unroll
    for (int mi = 0; mi < 4; ++mi) {
        const int grow = row0 + wr * 64 + mi * 16 + lg * 4;
#pragma unroll
        for (int r = 0; r < 4; ++r) {
            float* orow = mu + (size_t)(grow + r) * FCHUNK + col0 + wc * 64;
#pragma unroll
            for (int ni = 0; ni < 4; ++ni)
                orow[ni * 16 + lr] = acc[mi][ni][r] + bias[ni];
        }
    }
}

// ======================= running top-TOPC merge (exact radix select) ==========
#define EQCAP 128

__global__ __launch_bounds__(256) void topk_merge_kernel(
    const float* __restrict__ mu,
    float* __restrict__ run_val,
    int* __restrict__ run_idx,
    int chunk_base)
{
    const int row = blockIdx.x;
    const int tid = threadIdx.x;
    const int NTOT = FCHUNK + TOPC;

    __shared__ uint32_t uabs[FCHUNK + TOPC];
    __shared__ float oldv[TOPC];
    __shared__ int   oldi[TOPC];
    __shared__ int   hist[256];
    __shared__ uint32_t sh_prefix;
    __shared__ int   sh_cgt;
    __shared__ int   cnt_out, cnt_eq;
    __shared__ float newv[TOPC];
    __shared__ int   newi[TOPC];
    __shared__ int   eq_j[EQCAP];

    const float* murow = mu + (size_t)row * FCHUNK;

    for (int j = tid; j < FCHUNK; j += 256)
        uabs[j] = __float_as_uint(murow[j]) & 0x7fffffffu;
    if (tid < TOPC) {
        float v = run_val[row * TOPC + tid];
        int   g = run_idx[row * TOPC + tid];
        oldv[tid] = v; oldi[tid] = g;
        uabs[FCHUNK + tid] = (g >= 0) ? (__float_as_uint(v) & 0x7fffffffu) : 0u;
    }
    if (tid == 0) { sh_prefix = 0u; sh_cgt = 0; cnt_out = 0; cnt_eq = 0; }
    __syncthreads();

    for (int p = 3; p >= 0; --p) {
        hist[tid] = 0;
        __syncthreads();
        const uint32_t mask = (p == 3) ? 0u : (0xffffffffu << ((p + 1) * 8));
        const uint32_t pref = sh_prefix;
        for (int j = tid; j < NTOT; j += 256) {
            uint32_t u = uabs[j];
            if ((u & mask) == pref)
                atomicAdd(&hist[(u >> (p * 8)) & 255], 1);
        }
        __syncthreads();
        if (tid == 0) {
            int cum = sh_cgt;
            int chosen = 0;
            for (int b = 255; b >= 0; --b) {
                int c = hist[b];
                if (cum + c >= TOPC) { chosen = b; break; }
                cum += c;
            }
            sh_prefix = sh_prefix | ((uint32_t)chosen << (p * 8));
            sh_cgt = cum;
        }
        __syncthreads();
    }

    const uint32_t uth = sh_prefix;
    for (int j = tid; j < NTOT; j += 256) {
        uint32_t u = uabs[j];
        if (u > uth) {
            int pos = atomicAdd(&cnt_out, 1);
            if (j < FCHUNK) { newv[pos] = murow[j];          newi[pos] = chunk_base + j; }
            else            { newv[pos] = oldv[j - FCHUNK];  newi[pos] = oldi[j - FCHUNK]; }
        } else if (u == uth) {
            int e = atomicAdd(&cnt_eq, 1);
            if (e < EQCAP) eq_j[e] = j;
        }
    }
    __syncthreads();
    if (tid == 0) {
        int ne = cnt_eq < EQCAP ? cnt_eq : EQCAP;
        int need = TOPC - cnt_out;
        for (int s = 0; s < need; ++s) {
            int best = -1; long bestg = 0x7fffffffL;
            for (int t = 0; t < ne; ++t) {
                int j = eq_j[t];
                if (j < 0) continue;
                long g = (j < FCHUNK) ? (long)(chunk_base + j) : (long)oldi[j - FCHUNK];
                if (g < 0) g = 0x7ffffffeL;
                if (g < bestg) { bestg = g; best = t; }
            }
            if (best < 0) break;
            int j = eq_j[best]; eq_j[best] = -1;
            int pos = cnt_out + s;
            if (j < FCHUNK) { newv[pos] = murow[j];          newi[pos] = chunk_base + j; }
            else            { newv[pos] = oldv[j - FCHUNK];  newi[pos] = oldi[j - FCHUNK]; }
        }
    }
    __syncthreads();
    if (tid < TOPC) {
        run_val[row * TOPC + tid] = newv[tid];
        run_idx[row * TOPC + tid] = newi[tid];
    }
}

// ============ np.einsum-bit-exact refinement of TOPC candidates ==============
#define RGROUP 8
#define NROUND (TOPC / RGROUP)

__global__ __launch_bounds__(256) void refine_np_kernel(
    const float* __restrict__ x,
    const float* __restrict__ Wenc,
    const float* __restrict__ benc,
    const int* __restrict__ run_idx,
    float* __restrict__ sel_val,
    int* __restrict__ sel_idx)
{
    const int row  = blockIdx.x;
    const int tid  = threadIdx.x;
    const int wave = tid >> 6;
    const int lane = tid & 63;

    __shared__ __align__(16) float  xs[DIM];
    __shared__ __align__(16) float4 wslab4[RGROUP * (DIM / 4)];
    __shared__ float cval[TOPC];
    __shared__ int   cidx[TOPC];
    __shared__ float accs[RGROUP][4];

    {
        const float4* xr = (const float4*)(x + (size_t)row * DIM);
        for (int i = tid; i < DIM / 4; i += 256)
            ((float4*)xs)[i] = xr[i];
    }
    if (tid < TOPC) cidx[tid] = run_idx[row * TOPC + tid];
    __syncthreads();

    const float* wsl = (const float*)wslab4;

    for (int r = 0; r < NROUND; ++r) {
        const int c0 = r * RGROUP;
#pragma unroll
        for (int rr = 0; rr < RGROUP; ++rr) {
            int f = cidx[c0 + rr];
            if (f >= 0) {
                const float4* wr = (const float4*)(Wenc + (size_t)f * DIM);
                wslab4[rr * (DIM / 4) + tid]       = wr[tid];
                wslab4[rr * (DIM / 4) + 256 + tid] = wr[256 + tid];
            }
        }
        __syncthreads();
        if (lane < 8) {
            int cl = wave * 2 + (lane >> 2);
            int j  = lane & 3;
            int f  = cidx[c0 + cl];
            float a = 0.f;
            if (f >= 0) {
                const float* wrow = wsl + cl * DIM;
#pragma unroll 8
                for (int t = 0; t < DIM / 4; ++t) {
                    int d = (t << 2) | j;
                    a = __fadd_rn(a, __fmul_rn(xs[d], wrow[d]));
                }
            }
            accs[cl][j] = a;
        }
        __syncthreads();
        if (tid < RGROUP) {
            int f = cidx[c0 + tid];
            float v = __fadd_rn(__fadd_rn(accs[tid][0], accs[tid][2]),
                                __fadd_rn(accs[tid][1], accs[tid][3]));
            cval[c0 + tid] = (f >= 0) ? __fadd_rn(v, benc[f]) : 0.f;
        }
        __syncthreads();
    }

    if (tid < TOPC) {
        int f = cidx[tid];
        if (f >= 0) {
            uint32_t av = __float_as_uint(cval[tid]) & 0x7fffffffu;
            int rank = 0;
            for (int u = 0; u < TOPC; ++u) {
                if (u == tid) continue;
                int fu = cidx[u];
                if (fu < 0) continue;
                uint32_t au = __float_as_uint(cval[u]) & 0x7fffffffu;
                if (au > av || (au == av && fu < f)) ++rank;
            }
            if (rank < KSEL) {
                sel_val[row * KSEL + rank] = cval[tid];
                sel_idx[row * KSEL + rank] = f;
            }
        }
    }
}

// ======================= decode =======================
__global__ __launch_bounds__(256) void transpose_kernel(
    const float* __restrict__ Wdec,   // [DIM][FDICT]
    float* __restrict__ Wt,           // [FCHUNK][DIM]
    int chunk_base)
{
    __shared__ float t[32][33];
    const int j0 = blockIdx.x * 32;
    const int d0 = blockIdx.y * 32;
    const int tx = threadIdx.x & 31;
    const int ty = threadIdx.x >> 5;
#pragma unroll
    for (int r = 0; r < 4; ++r)
        t[ty + 8 * r][tx] = Wdec[(size_t)(d0 + ty + 8 * r) * FDICT + chunk_base + j0 + tx];
    __syncthreads();
#pragma unroll
    for (int r = 0; r < 4; ++r)
        Wt[(size_t)(j0 + ty + 8 * r) * DIM + d0 + tx] = t[tx][ty + 8 * r];
}

__global__ __launch_bounds__(256) void init_out_kernel(
    float* __restrict__ out, const float* __restrict__ bdec)
{
    int i = blockIdx.x * 256 + threadIdx.x;
    out[i] = bdec[i & (DIM - 1)];
}

__global__ __launch_bounds__(256) void init_topk_kernel(
    float* __restrict__ run_val, int* __restrict__ run_idx)
{
    int i = blockIdx.x * 256 + threadIdx.x;
    if (i < B_ROWS * TOPC) { run_val[i] = 0.f; run_idx[i] = -1; }
}

__global__ __launch_bounds__(256) void decode_kernel(
    const float* __restrict__ Wt,       // [FCHUNK][DIM] transposed chunk
    const float* __restrict__ sel_val,
    const int* __restrict__ sel_idx,
    float* __restrict__ out,
    int chunk_base)
{
    const int row = blockIdx.x;
    const int tid = threadIdx.x;
    __shared__ float vv[KSEL];
    __shared__ int   ff[KSEL];
    if (tid < KSEL) {
        vv[tid] = sel_val[row * KSEL + tid];
        ff[tid] = sel_idx[row * KSEL + tid] - chunk_base;
    }
    __syncthreads();
    float acc[8] = {0.f, 0.f, 0.f, 0.f, 0.f, 0.f, 0.f, 0.f};
    for (int k = 0; k < KSEL; ++k) {
        int f = ff[k];
        if (0 <= f && f < FCHUNK) {
            float v = vv[k];
            const float* wrow = Wt + (size_t)f * DIM;
#pragma unroll
            for (int i = 0; i < 8; ++i)
                acc[i] += v * wrow[tid + 256 * i];
        }
    }
    float* orow = out + (size_t)row * DIM;
#pragma unroll
    for (int i = 0; i < 8; ++i)
        orow[tid + 256 * i] += acc[i];
}

// ======================= launch =======================
extern "C" void kernel_launch(void* const* d_in, const int* in_sizes, int n_in,
                              void* d_out, int out_size, void* d_ws, size_t ws_size,
                              hipStream_t stream)
{
    const float* x    = (const float*)d_in[0];
    const float* Wenc = (const float*)d_in[1];
    const float* benc = (const float*)d_in[2];
    const float* Wdec = (const float*)d_in[3];
    const float* bdec = (const float*)d_in[4];
    (void)in_sizes; (void)n_in; (void)out_size; (void)ws_size;
    float* out = (float*)d_out;

    char* ws = (char*)d_ws;
    size_t off = 0;
    float* buf0    = (float*)(ws + off); off += (size_t)B_ROWS * FCHUNK * 4;  // 64 MB
    float* run_val = (float*)(ws + off); off += (size_t)B_ROWS * TOPC * 4;
    int*   run_idx = (int*)  (ws + off); off += (size_t)B_ROWS * TOPC * 4;
    float* sel_val = (float*)(ws + off); off += (size_t)B_ROWS * KSEL * 4;
    int*   sel_idx = (int*)  (ws + off); off += (size_t)B_ROWS * KSEL * 4;

    init_topk_kernel<<<(B_ROWS * TOPC + 255) / 256, 256, 0, stream>>>(run_val, run_idx);
    for (int c = 0; c < NCHUNK; ++c) {
        enc_gemm_mfma<<<dim3(FCHUNK / TN, B_ROWS / TM), 256, 0, stream>>>(
            x, Wenc, benc, buf0, c * FCHUNK);
        topk_merge_kernel<<<B_ROWS, 256, 0, stream>>>(buf0, run_val, run_idx, c * FCHUNK);
    }
    refine_np_kernel<<<B_ROWS, 256, 0, stream>>>(x, Wenc, benc, run_idx, sel_val, sel_idx);
    init_out_kernel<<<(B_ROWS * DIM) / 256, 256, 0, stream>>>(out, bdec);
    for (int c = 0; c < NCHUNK; ++c) {
        transpose_kernel<<<dim3(FCHUNK / 32, DIM / 32), 256, 0, stream>>>(
            Wdec, buf0, c * FCHUNK);
        decode_kernel<<<B_ROWS, 256, 0, stream>>>(buf0, sel_val, sel_idx, out, c * FCHUNK);
    }
}

// Round 5
// 1724.383 us; speedup vs baseline: 2.8584x; 1.2990x over previous
//
#include <hip/hip_runtime.h>
#include <stdint.h>

#define B_ROWS 2048
#define DIM    2048
#define FDICT  32768
#define KSEL   64
#define TOPC   96      // candidate list; refined bit-exactly vs np.einsum fp32
#define FCHUNK 4096
#define NCHUNK (FDICT / FCHUNK)

typedef __attribute__((ext_vector_type(8))) short bf16x8;
typedef __attribute__((ext_vector_type(4))) float f32x4;

// -------- fp32 -> bf16 (RNE) streaming convert --------
__global__ __launch_bounds__(256) void conv_bf16_kernel(
    const float* __restrict__ src, ushort* __restrict__ dst)
{
    const size_t i = ((size_t)blockIdx.x * 256 + threadIdx.x) * 8;
    float4 u = *(const float4*)(src + i);
    float4 v = *(const float4*)(src + i + 4);
    union { ushort s[8]; bf16x8 w; } o;
    float t[8] = {u.x, u.y, u.z, u.w, v.x, v.y, v.z, v.w};
#pragma unroll
    for (int j = 0; j < 8; ++j) {
        union { __bf16 h; ushort s; } cv;
        cv.h = (__bf16)t[j];
        o.s[j] = cv.s;
    }
    *(bf16x8*)(dst + i) = o.w;
}

// =================== encode GEMM (bf16 MFMA, m97 structure) ===================
// mu_approx[b, j] = dot(bf16(x[b,:]), bf16(Wenc[j,:])) + benc[j], fp32 accum.
// Candidate generation only; refine_np re-derives exact values.
#define GM 128
#define GN 128
#define GK 64    // bf16 elems per K-tile; LDS tiles 128x64 linear (global_load_lds)

__device__ __forceinline__ void gload_lds16(const void* g, void* l)
{
    __builtin_amdgcn_global_load_lds(
        (const __attribute__((address_space(1))) void*)(uintptr_t)g,
        (__attribute__((address_space(3))) void*)(uint32_t)(uintptr_t)l,
        16, 0, 0);
}

__global__ __launch_bounds__(256) void enc_gemm_bt(
    const ushort* __restrict__ A,    // x_bf16   [B_ROWS][DIM]
    const ushort* __restrict__ Bw,   // wchunk   [FCHUNK][DIM]
    const float* __restrict__ benc,
    float* __restrict__ mu,          // [B_ROWS][FCHUNK]
    int chunk_base)
{
    __shared__ __align__(16) ushort As[GM * GK];
    __shared__ __align__(16) ushort Bs[GN * GK];

    const int tid  = threadIdx.x;
    const int lane = tid & 63;
    const int wv   = tid >> 6;
    const int wr   = wv >> 1, wc = wv & 1;     // 2x2 wave grid, 64x64 per wave
    const int lr   = lane & 15, lg = lane >> 4;
    const int row0 = blockIdx.y * GM;
    const int col0 = blockIdx.x * GN;

    const ushort* aSrc = A  + (size_t)row0 * DIM;
    const ushort* bSrc = Bw + (size_t)col0 * DIM;

    const int srow = (lane >> 3);        // 0..7 row within 8-row group
    const int scol = (lane & 7) * 8;     // element col of this lane's 16B

    f32x4 acc[4][4] = {};

    for (int kt = 0; kt < DIM / GK; ++kt) {
        const int k0 = kt * GK;
        __syncthreads();   // previous K-tile's reads complete before overwrite
#pragma unroll
        for (int i = 0; i < 4; ++i) {
            const int g = wv * 4 + i;                 // 8-row group 0..15
            const int r = g * 8 + srow;
            gload_lds16(aSrc + (size_t)r * DIM + k0 + scol, (char*)As + g * 1024);
            gload_lds16(bSrc + (size_t)r * DIM + k0 + scol, (char*)Bs + g * 1024);
        }
        __syncthreads();   // vmcnt(0) drain -> staged tile visible

        bf16x8 af[2][4], bfr[2][4];
#pragma unroll
        for (int kk = 0; kk < 2; ++kk) {
#pragma unroll
            for (int mi = 0; mi < 4; ++mi)
                af[kk][mi] = *(const bf16x8*)(As + (wr * 64 + mi * 16 + lr) * GK + kk * 32 + lg * 8);
#pragma unroll
            for (int ni = 0; ni < 4; ++ni)
                bfr[kk][ni] = *(const bf16x8*)(Bs + (wc * 64 + ni * 16 + lr) * GK + kk * 32 + lg * 8);
        }
#pragma unroll
        for (int kk = 0; kk < 2; ++kk)
#pragma unroll
            for (int mi = 0; mi < 4; ++mi)
#pragma unroll
                for (int ni = 0; ni < 4; ++ni)
                    acc[mi][ni] = __builtin_amdgcn_mfma_f32_16x16x32_bf16(
                        af[kk][mi], bfr[kk][ni], acc[mi][ni], 0, 0, 0);
    }

    float bias[4];
#pragma unroll
    for (int ni = 0; ni < 4; ++ni)
        bias[ni] = benc[chunk_base + col0 + wc * 64 + ni * 16 + lr];
    // C/D layout (verified round 4): col = lane&15, row = (lane>>4)*4 + reg
#pragma unroll
    for (int mi = 0; mi < 4; ++mi) {
        const int grow = row0 + wr * 64 + mi * 16 + lg * 4;
#pragma unroll
        for (int r = 0; r < 4; ++r) {
            float* orow = mu + (size_t)(grow + r) * FCHUNK + col0 + wc * 64;
#pragma unroll
            for (int ni = 0; ni < 4; ++ni)
                orow[ni * 16 + lr] = acc[mi][ni][r] + bias[ni];
        }
    }
}

// ======================= running top-TOPC merge (exact radix select) ==========
#define EQCAP 128

__global__ __launch_bounds__(256) void topk_merge_kernel(
    const float* __restrict__ mu,
    float* __restrict__ run_val,
    int* __restrict__ run_idx,
    int chunk_base)
{
    const int row = blockIdx.x;
    const int tid = threadIdx.x;
    const int NTOT = FCHUNK + TOPC;

    __shared__ uint32_t uabs[FCHUNK + TOPC];
    __shared__ float oldv[TOPC];
    __shared__ int   oldi[TOPC];
    __shared__ int   hist[256];
    __shared__ uint32_t sh_prefix;
    __shared__ int   sh_cgt;
    __shared__ int   cnt_out, cnt_eq;
    __shared__ float newv[TOPC];
    __shared__ int   newi[TOPC];
    __shared__ int   eq_j[EQCAP];

    const float* murow = mu + (size_t)row * FCHUNK;

    for (int j = tid; j < FCHUNK; j += 256)
        uabs[j] = __float_as_uint(murow[j]) & 0x7fffffffu;
    if (tid < TOPC) {
        float v = run_val[row * TOPC + tid];
        int   g = run_idx[row * TOPC + tid];
        oldv[tid] = v; oldi[tid] = g;
        uabs[FCHUNK + tid] = (g >= 0) ? (__float_as_uint(v) & 0x7fffffffu) : 0u;
    }
    if (tid == 0) { sh_prefix = 0u; sh_cgt = 0; cnt_out = 0; cnt_eq = 0; }
    __syncthreads();

    for (int p = 3; p >= 0; --p) {
        hist[tid] = 0;
        __syncthreads();
        const uint32_t mask = (p == 3) ? 0u : (0xffffffffu << ((p + 1) * 8));
        const uint32_t pref = sh_prefix;
        for (int j = tid; j < NTOT; j += 256) {
            uint32_t u = uabs[j];
            if ((u & mask) == pref)
                atomicAdd(&hist[(u >> (p * 8)) & 255], 1);
        }
        __syncthreads();
        if (tid == 0) {
            int cum = sh_cgt;
            int chosen = 0;
            for (int b = 255; b >= 0; --b) {
                int c = hist[b];
                if (cum + c >= TOPC) { chosen = b; break; }
                cum += c;
            }
            sh_prefix = sh_prefix | ((uint32_t)chosen << (p * 8));
            sh_cgt = cum;
        }
        __syncthreads();
    }

    const uint32_t uth = sh_prefix;
    for (int j = tid; j < NTOT; j += 256) {
        uint32_t u = uabs[j];
        if (u > uth) {
            int pos = atomicAdd(&cnt_out, 1);
            if (j < FCHUNK) { newv[pos] = murow[j];          newi[pos] = chunk_base + j; }
            else            { newv[pos] = oldv[j - FCHUNK];  newi[pos] = oldi[j - FCHUNK]; }
        } else if (u == uth) {
            int e = atomicAdd(&cnt_eq, 1);
            if (e < EQCAP) eq_j[e] = j;
        }
    }
    __syncthreads();
    if (tid == 0) {
        int ne = cnt_eq < EQCAP ? cnt_eq : EQCAP;
        int need = TOPC - cnt_out;
        for (int s = 0; s < need; ++s) {
            int best = -1; long bestg = 0x7fffffffL;
            for (int t = 0; t < ne; ++t) {
                int j = eq_j[t];
                if (j < 0) continue;
                long g = (j < FCHUNK) ? (long)(chunk_base + j) : (long)oldi[j - FCHUNK];
                if (g < 0) g = 0x7ffffffeL;
                if (g < bestg) { bestg = g; best = t; }
            }
            if (best < 0) break;
            int j = eq_j[best]; eq_j[best] = -1;
            int pos = cnt_out + s;
            if (j < FCHUNK) { newv[pos] = murow[j];          newi[pos] = chunk_base + j; }
            else            { newv[pos] = oldv[j - FCHUNK];  newi[pos] = oldi[j - FCHUNK]; }
        }
    }
    __syncthreads();
    if (tid < TOPC) {
        run_val[row * TOPC + tid] = newv[tid];
        run_idx[row * TOPC + tid] = newi[tid];
    }
}

// ============ np.einsum-bit-exact refinement of TOPC candidates ==============
// numpy fp32 SSE chain: 4 accumulators over d%4 ascending, round(mul) then
// round(add) (no FMA), combined (a0+a2)+(a1+a3), then + b_enc.
// One thread per candidate, float4 row loads -> 4 interleaved serial chains.
__global__ __launch_bounds__(256) void refine_np_kernel(
    const float* __restrict__ x,
    const float* __restrict__ Wenc,
    const float* __restrict__ benc,
    const int* __restrict__ run_idx,
    float* __restrict__ sel_val,
    int* __restrict__ sel_idx)
{
    const int half = threadIdx.x >> 7;      // row within block (0..1)
    const int cid  = threadIdx.x & 127;     // candidate id (<TOPC active)
    const int row  = blockIdx.x * 2 + half;

    __shared__ __align__(16) float xs[2][DIM];
    __shared__ float cval[2][TOPC];
    __shared__ int   cidx[2][TOPC];

    {
        const float4* src = (const float4*)(x + (size_t)blockIdx.x * 2 * DIM);
        for (int i = threadIdx.x; i < 2 * DIM / 4; i += 256)
            ((float4*)xs)[i] = src[i];
    }
    if (cid < TOPC) cidx[half][cid] = run_idx[(size_t)row * TOPC + cid];
    __syncthreads();

    if (cid < TOPC) {
        const int f = cidx[half][cid];
        const float4* w4 = (const float4*)(Wenc + (size_t)f * DIM);
        const float4* x4 = (const float4*)xs[half];
        float a0 = 0.f, a1 = 0.f, a2 = 0.f, a3 = 0.f;
#pragma unroll 4
        for (int t = 0; t < DIM / 4; ++t) {
            float4 wv = w4[t];
            float4 xv = x4[t];
            a0 = __fadd_rn(a0, __fmul_rn(xv.x, wv.x));
            a1 = __fadd_rn(a1, __fmul_rn(xv.y, wv.y));
            a2 = __fadd_rn(a2, __fmul_rn(xv.z, wv.z));
            a3 = __fadd_rn(a3, __fmul_rn(xv.w, wv.w));
        }
        float v = __fadd_rn(__fadd_rn(a0, a2), __fadd_rn(a1, a3));
        cval[half][cid] = __fadd_rn(v, benc[f]);
    }
    __syncthreads();

    if (cid < TOPC) {
        const int f = cidx[half][cid];
        const uint32_t av = __float_as_uint(cval[half][cid]) & 0x7fffffffu;
        int rank = 0;
        for (int u = 0; u < TOPC; ++u) {
            if (u == cid) continue;
            int fu = cidx[half][u];
            uint32_t au = __float_as_uint(cval[half][u]) & 0x7fffffffu;
            if (au > av || (au == av && fu < f)) ++rank;
        }
        if (rank < KSEL) {
            sel_val[(size_t)row * KSEL + rank] = cval[half][cid];
            sel_idx[(size_t)row * KSEL + rank] = f;
        }
    }
}

// ======================= decode =======================
__global__ __launch_bounds__(256) void transpose_kernel(
    const float* __restrict__ Wdec,   // [DIM][FDICT]
    float* __restrict__ Wt,           // [FCHUNK][DIM]
    int chunk_base)
{
    __shared__ float t[32][33];
    const int j0 = blockIdx.x * 32;
    const int d0 = blockIdx.y * 32;
    const int tx = threadIdx.x & 31;
    const int ty = threadIdx.x >> 5;
#pragma unroll
    for (int r = 0; r < 4; ++r)
        t[ty + 8 * r][tx] = Wdec[(size_t)(d0 + ty + 8 * r) * FDICT + chunk_base + j0 + tx];
    __syncthreads();
#pragma unroll
    for (int r = 0; r < 4; ++r)
        Wt[(size_t)(j0 + ty + 8 * r) * DIM + d0 + tx] = t[tx][ty + 8 * r];
}

__global__ __launch_bounds__(256) void init_out_kernel(
    float* __restrict__ out, const float* __restrict__ bdec)
{
    int i = blockIdx.x * 256 + threadIdx.x;
    out[i] = bdec[i & (DIM - 1)];
}

__global__ __launch_bounds__(256) void init_topk_kernel(
    float* __restrict__ run_val, int* __restrict__ run_idx)
{
    int i = blockIdx.x * 256 + threadIdx.x;
    if (i < B_ROWS * TOPC) { run_val[i] = 0.f; run_idx[i] = -1; }
}

__global__ __launch_bounds__(256) void decode_kernel(
    const float* __restrict__ Wt,       // [FCHUNK][DIM] transposed chunk
    const float* __restrict__ sel_val,
    const int* __restrict__ sel_idx,
    float* __restrict__ out,
    int chunk_base)
{
    const int row = blockIdx.x;
    const int tid = threadIdx.x;
    __shared__ float vv[KSEL];
    __shared__ int   ff[KSEL];
    if (tid < KSEL) {
        vv[tid] = sel_val[row * KSEL + tid];
        ff[tid] = sel_idx[row * KSEL + tid] - chunk_base;
    }
    __syncthreads();
    float acc[8] = {0.f, 0.f, 0.f, 0.f, 0.f, 0.f, 0.f, 0.f};
    for (int k = 0; k < KSEL; ++k) {
        int f = ff[k];
        if (0 <= f && f < FCHUNK) {
            float v = vv[k];
            const float* wrow = Wt + (size_t)f * DIM;
#pragma unroll
            for (int i = 0; i < 8; ++i)
                acc[i] += v * wrow[tid + 256 * i];
        }
    }
    float* orow = out + (size_t)row * DIM;
#pragma unroll
    for (int i = 0; i < 8; ++i)
        orow[tid + 256 * i] += acc[i];
}

// ======================= launch =======================
extern "C" void kernel_launch(void* const* d_in, const int* in_sizes, int n_in,
                              void* d_out, int out_size, void* d_ws, size_t ws_size,
                              hipStream_t stream)
{
    const float* x    = (const float*)d_in[0];
    const float* Wenc = (const float*)d_in[1];
    const float* benc = (const float*)d_in[2];
    const float* Wdec = (const float*)d_in[3];
    const float* bdec = (const float*)d_in[4];
    (void)in_sizes; (void)n_in; (void)out_size; (void)ws_size;
    float* out = (float*)d_out;

    char* ws = (char*)d_ws;
    size_t off = 0;
    float*  buf0    = (float*)(ws + off);  off += (size_t)B_ROWS * FCHUNK * 4;   // 32 MB: mu chunk / Wt chunk
    ushort* wchunk  = (ushort*)(ws + off); off += (size_t)FCHUNK * DIM * 2;      // 16 MB: bf16 Wenc chunk
    ushort* x_bf16  = (ushort*)(ws + off); off += (size_t)B_ROWS * DIM * 2;      //  8 MB
    float*  run_val = (float*)(ws + off);  off += (size_t)B_ROWS * TOPC * 4;
    int*    run_idx = (int*)(ws + off);    off += (size_t)B_ROWS * TOPC * 4;
    float*  sel_val = (float*)(ws + off);  off += (size_t)B_ROWS * KSEL * 4;
    int*    sel_idx = (int*)(ws + off);    off += (size_t)B_ROWS * KSEL * 4;

    init_topk_kernel<<<(B_ROWS * TOPC + 255) / 256, 256, 0, stream>>>(run_val, run_idx);
    conv_bf16_kernel<<<(B_ROWS * DIM) / (256 * 8), 256, 0, stream>>>(x, x_bf16);

    for (int c = 0; c < NCHUNK; ++c) {
        conv_bf16_kernel<<<((size_t)FCHUNK * DIM) / (256 * 8), 256, 0, stream>>>(
            Wenc + (size_t)c * FCHUNK * DIM, wchunk);
        enc_gemm_bt<<<dim3(FCHUNK / GN, B_ROWS / GM), 256, 0, stream>>>(
            x_bf16, wchunk, benc, buf0, c * FCHUNK);
        topk_merge_kernel<<<B_ROWS, 256, 0, stream>>>(buf0, run_val, run_idx, c * FCHUNK);
    }

    refine_np_kernel<<<B_ROWS / 2, 256, 0, stream>>>(x, Wenc, benc, run_idx, sel_val, sel_idx);

    init_out_kernel<<<(B_ROWS * DIM) / 256, 256, 0, stream>>>(out, bdec);
    for (int c = 0; c < NCHUNK; ++c) {
        transpose_kernel<<<dim3(FCHUNK / 32, DIM / 32), 256, 0, stream>>>(
            Wdec, buf0, c * FCHUNK);
        decode_kernel<<<B_ROWS, 256, 0, stream>>>(buf0, sel_val, sel_idx, out, c * FCHUNK);
    }
}

// Round 6
// 1536.737 us; speedup vs baseline: 3.2075x; 1.1221x over previous
//
#include <hip/hip_runtime.h>
#include <stdint.h>

#define B_ROWS 2048
#define DIM    2048
#define FDICT  32768
#define KSEL   64
#define TOPC   96      // candidate list; refined bit-exactly vs np.einsum fp32
#define FCHUNK 4096
#define NCHUNK (FDICT / FCHUNK)

typedef __attribute__((ext_vector_type(8))) short bf16x8;
typedef __attribute__((ext_vector_type(4))) float f32x4;

__device__ __forceinline__ float bf16_to_f32(ushort u)
{
    return __uint_as_float(((uint32_t)u) << 16);
}

// -------- fp32 -> bf16 (RNE) streaming convert --------
__global__ __launch_bounds__(256) void conv_bf16_kernel(
    const float* __restrict__ src, ushort* __restrict__ dst)
{
    const size_t i = ((size_t)blockIdx.x * 256 + threadIdx.x) * 8;
    float4 u = *(const float4*)(src + i);
    float4 v = *(const float4*)(src + i + 4);
    union { ushort s[8]; bf16x8 w; } o;
    float t[8] = {u.x, u.y, u.z, u.w, v.x, v.y, v.z, v.w};
#pragma unroll
    for (int j = 0; j < 8; ++j) {
        union { __bf16 h; ushort s; } cv;
        cv.h = (__bf16)t[j];
        o.s[j] = cv.s;
    }
    *(bf16x8*)(dst + i) = o.w;
}

// =================== encode GEMM (bf16 MFMA, m97 structure) ===================
#define GM 128
#define GN 128
#define GK 64

__device__ __forceinline__ void gload_lds16(const void* g, void* l)
{
    __builtin_amdgcn_global_load_lds(
        (const __attribute__((address_space(1))) void*)(uintptr_t)g,
        (__attribute__((address_space(3))) void*)(uint32_t)(uintptr_t)l,
        16, 0, 0);
}

__global__ __launch_bounds__(256) void enc_gemm_bt(
    const ushort* __restrict__ A,    // x_bf16   [B_ROWS][DIM]
    const ushort* __restrict__ Bw,   // Wenc_bf16 chunk base [FCHUNK][DIM]
    const float* __restrict__ benc,
    float* __restrict__ mu,          // [B_ROWS][FCHUNK]
    int chunk_base)
{
    __shared__ __align__(16) ushort As[GM * GK];
    __shared__ __align__(16) ushort Bs[GN * GK];

    const int tid  = threadIdx.x;
    const int lane = tid & 63;
    const int wv   = tid >> 6;
    const int wr   = wv >> 1, wc = wv & 1;
    const int lr   = lane & 15, lg = lane >> 4;
    const int row0 = blockIdx.y * GM;
    const int col0 = blockIdx.x * GN;

    const ushort* aSrc = A  + (size_t)row0 * DIM;
    const ushort* bSrc = Bw + (size_t)col0 * DIM;

    const int srow = (lane >> 3);
    const int scol = (lane & 7) * 8;

    f32x4 acc[4][4] = {};

    for (int kt = 0; kt < DIM / GK; ++kt) {
        const int k0 = kt * GK;
        __syncthreads();
#pragma unroll
        for (int i = 0; i < 4; ++i) {
            const int g = wv * 4 + i;
            const int r = g * 8 + srow;
            gload_lds16(aSrc + (size_t)r * DIM + k0 + scol, (char*)As + g * 1024);
            gload_lds16(bSrc + (size_t)r * DIM + k0 + scol, (char*)Bs + g * 1024);
        }
        __syncthreads();

        bf16x8 af[2][4], bfr[2][4];
#pragma unroll
        for (int kk = 0; kk < 2; ++kk) {
#pragma unroll
            for (int mi = 0; mi < 4; ++mi)
                af[kk][mi] = *(const bf16x8*)(As + (wr * 64 + mi * 16 + lr) * GK + kk * 32 + lg * 8);
#pragma unroll
            for (int ni = 0; ni < 4; ++ni)
                bfr[kk][ni] = *(const bf16x8*)(Bs + (wc * 64 + ni * 16 + lr) * GK + kk * 32 + lg * 8);
        }
#pragma unroll
        for (int kk = 0; kk < 2; ++kk)
#pragma unroll
            for (int mi = 0; mi < 4; ++mi)
#pragma unroll
                for (int ni = 0; ni < 4; ++ni)
                    acc[mi][ni] = __builtin_amdgcn_mfma_f32_16x16x32_bf16(
                        af[kk][mi], bfr[kk][ni], acc[mi][ni], 0, 0, 0);
    }

    float bias[4];
#pragma unroll
    for (int ni = 0; ni < 4; ++ni)
        bias[ni] = benc[chunk_base + col0 + wc * 64 + ni * 16 + lr];
#pragma unroll
    for (int mi = 0; mi < 4; ++mi) {
        const int grow = row0 + wr * 64 + mi * 16 + lg * 4;
#pragma unroll
        for (int r = 0; r < 4; ++r) {
            float* orow = mu + (size_t)(grow + r) * FCHUNK + col0 + wc * 64;
#pragma unroll
            for (int ni = 0; ni < 4; ++ni)
                orow[ni * 16 + lr] = acc[mi][ni][r] + bias[ni];
        }
    }
}

// ======================= running top-TOPC merge (exact radix select) ==========
#define EQCAP 128

__global__ __launch_bounds__(256) void topk_merge_kernel(
    const float* __restrict__ mu,
    float* __restrict__ run_val,
    int* __restrict__ run_idx,
    int chunk_base)
{
    const int row = blockIdx.x;
    const int tid = threadIdx.x;
    const int NTOT = FCHUNK + TOPC;

    __shared__ uint32_t uabs[FCHUNK + TOPC];
    __shared__ float oldv[TOPC];
    __shared__ int   oldi[TOPC];
    __shared__ int   hist[256];
    __shared__ uint32_t sh_prefix;
    __shared__ int   sh_cgt;
    __shared__ int   cnt_out, cnt_eq;
    __shared__ float newv[TOPC];
    __shared__ int   newi[TOPC];
    __shared__ int   eq_j[EQCAP];

    const float* murow = mu + (size_t)row * FCHUNK;

    for (int j = tid; j < FCHUNK; j += 256)
        uabs[j] = __float_as_uint(murow[j]) & 0x7fffffffu;
    if (tid < TOPC) {
        float v = run_val[row * TOPC + tid];
        int   g = run_idx[row * TOPC + tid];
        oldv[tid] = v; oldi[tid] = g;
        uabs[FCHUNK + tid] = (g >= 0) ? (__float_as_uint(v) & 0x7fffffffu) : 0u;
    }
    if (tid == 0) { sh_prefix = 0u; sh_cgt = 0; cnt_out = 0; cnt_eq = 0; }
    __syncthreads();

    for (int p = 3; p >= 0; --p) {
        hist[tid] = 0;
        __syncthreads();
        const uint32_t mask = (p == 3) ? 0u : (0xffffffffu << ((p + 1) * 8));
        const uint32_t pref = sh_prefix;
        for (int j = tid; j < NTOT; j += 256) {
            uint32_t u = uabs[j];
            if ((u & mask) == pref)
                atomicAdd(&hist[(u >> (p * 8)) & 255], 1);
        }
        __syncthreads();
        if (tid == 0) {
            int cum = sh_cgt;
            int chosen = 0;
            for (int b = 255; b >= 0; --b) {
                int c = hist[b];
                if (cum + c >= TOPC) { chosen = b; break; }
                cum += c;
            }
            sh_prefix = sh_prefix | ((uint32_t)chosen << (p * 8));
            sh_cgt = cum;
        }
        __syncthreads();
    }

    const uint32_t uth = sh_prefix;
    for (int j = tid; j < NTOT; j += 256) {
        uint32_t u = uabs[j];
        if (u > uth) {
            int pos = atomicAdd(&cnt_out, 1);
            if (j < FCHUNK) { newv[pos] = murow[j];          newi[pos] = chunk_base + j; }
            else            { newv[pos] = oldv[j - FCHUNK];  newi[pos] = oldi[j - FCHUNK]; }
        } else if (u == uth) {
            int e = atomicAdd(&cnt_eq, 1);
            if (e < EQCAP) eq_j[e] = j;
        }
    }
    __syncthreads();
    if (tid == 0) {
        int ne = cnt_eq < EQCAP ? cnt_eq : EQCAP;
        int need = TOPC - cnt_out;
        for (int s = 0; s < need; ++s) {
            int best = -1; long bestg = 0x7fffffffL;
            for (int t = 0; t < ne; ++t) {
                int j = eq_j[t];
                if (j < 0) continue;
                long g = (j < FCHUNK) ? (long)(chunk_base + j) : (long)oldi[j - FCHUNK];
                if (g < 0) g = 0x7ffffffeL;
                if (g < bestg) { bestg = g; best = t; }
            }
            if (best < 0) break;
            int j = eq_j[best]; eq_j[best] = -1;
            int pos = cnt_out + s;
            if (j < FCHUNK) { newv[pos] = murow[j];          newi[pos] = chunk_base + j; }
            else            { newv[pos] = oldv[j - FCHUNK];  newi[pos] = oldi[j - FCHUNK]; }
        }
    }
    __syncthreads();
    if (tid < TOPC) {
        run_val[row * TOPC + tid] = newv[tid];
        run_idx[row * TOPC + tid] = newi[tid];
    }
}

// ============ np.einsum-bit-exact refinement of TOPC candidates ==============
// numpy fp32 SSE chain: 4 accumulators over d%4 ascending, round(mul) then
// round(add) (no FMA), combined (a0+a2)+(a1+a3), then + b_enc.
// One thread/candidate; 8 batched float4 loads -> high memory-level parallelism.
__global__ __launch_bounds__(256) void refine_np_kernel(
    const float* __restrict__ x,
    const float* __restrict__ Wenc,
    const float* __restrict__ benc,
    const int* __restrict__ run_idx,
    float* __restrict__ sel_val,
    int* __restrict__ sel_idx)
{
    const int half = threadIdx.x >> 7;      // row within block (0..1)
    const int cid  = threadIdx.x & 127;     // candidate id (<TOPC active)
    const int row  = blockIdx.x * 2 + half;

    __shared__ __align__(16) float xs[2][DIM];
    __shared__ float cval[2][TOPC];
    __shared__ int   cidx[2][TOPC];

    {
        const float4* src = (const float4*)(x + (size_t)blockIdx.x * 2 * DIM);
        for (int i = threadIdx.x; i < 2 * DIM / 4; i += 256)
            ((float4*)xs)[i] = src[i];
    }
    if (cid < TOPC) cidx[half][cid] = run_idx[(size_t)row * TOPC + cid];
    __syncthreads();

    if (cid < TOPC) {
        const int f = cidx[half][cid];
        const float4* w4 = (const float4*)(Wenc + (size_t)f * DIM);
        const float4* x4 = (const float4*)xs[half];
        float a0 = 0.f, a1 = 0.f, a2 = 0.f, a3 = 0.f;
#pragma unroll 2
        for (int t0 = 0; t0 < DIM / 4; t0 += 8) {
            float4 wb[8];
#pragma unroll
            for (int u = 0; u < 8; ++u) wb[u] = w4[t0 + u];   // 8 loads in flight
#pragma unroll
            for (int u = 0; u < 8; ++u) {
                float4 xv = x4[t0 + u];                        // LDS broadcast
                a0 = __fadd_rn(a0, __fmul_rn(xv.x, wb[u].x));
                a1 = __fadd_rn(a1, __fmul_rn(xv.y, wb[u].y));
                a2 = __fadd_rn(a2, __fmul_rn(xv.z, wb[u].z));
                a3 = __fadd_rn(a3, __fmul_rn(xv.w, wb[u].w));
            }
        }
        float v = __fadd_rn(__fadd_rn(a0, a2), __fadd_rn(a1, a3));
        cval[half][cid] = __fadd_rn(v, benc[f]);
    }
    __syncthreads();

    if (cid < TOPC) {
        const int f = cidx[half][cid];
        const uint32_t av = __float_as_uint(cval[half][cid]) & 0x7fffffffu;
        int rank = 0;
        for (int u = 0; u < TOPC; ++u) {
            if (u == cid) continue;
            int fu = cidx[half][u];
            uint32_t au = __float_as_uint(cval[half][u]) & 0x7fffffffu;
            if (au > av || (au == av && fu < f)) ++rank;
        }
        if (rank < KSEL) {
            sel_val[(size_t)row * KSEL + rank] = cval[half][cid];
            sel_idx[(size_t)row * KSEL + rank] = f;
        }
    }
}

// ================= decode, FULL path: Wdec -> bf16 [F][D], one pass ==========
__global__ __launch_bounds__(256) void transpose_wdec_bf16(
    const float* __restrict__ Wdec,   // [DIM][FDICT]
    ushort* __restrict__ WdecT)       // [FDICT][DIM] bf16
{
    __shared__ float t[64][65];
    const int f0 = blockIdx.x * 64;
    const int d0 = blockIdx.y * 64;
    const int tx = threadIdx.x & 63;
    const int ty = threadIdx.x >> 6;  // 0..3
#pragma unroll
    for (int r = 0; r < 16; ++r)
        t[ty * 16 + r][tx] = Wdec[(size_t)(d0 + ty * 16 + r) * FDICT + f0 + tx];
    __syncthreads();
#pragma unroll
    for (int r = 0; r < 16; ++r) {
        union { __bf16 h; ushort s; } cv;
        cv.h = (__bf16)t[tx][ty * 16 + r];
        WdecT[(size_t)(f0 + ty * 16 + r) * DIM + d0 + tx] = cv.s;
    }
}

__global__ __launch_bounds__(256) void decode_full_kernel(
    const ushort* __restrict__ WdecT,   // [FDICT][DIM] bf16
    const float* __restrict__ sel_val,
    const int* __restrict__ sel_idx,
    const float* __restrict__ bdec,
    float* __restrict__ out)
{
    const int row = blockIdx.x;
    const int tid = threadIdx.x;
    __shared__ float vv[KSEL];
    __shared__ int   ff[KSEL];
    if (tid < KSEL) {
        vv[tid] = sel_val[row * KSEL + tid];
        ff[tid] = sel_idx[row * KSEL + tid];
    }
    __syncthreads();
    const int d0 = tid * 8;
    float acc[8];
    {
        float4 b0 = *(const float4*)(bdec + d0);
        float4 b1 = *(const float4*)(bdec + d0 + 4);
        acc[0] = b0.x; acc[1] = b0.y; acc[2] = b0.z; acc[3] = b0.w;
        acc[4] = b1.x; acc[5] = b1.y; acc[6] = b1.z; acc[7] = b1.w;
    }
    for (int k = 0; k < KSEL; ++k) {
        const float v = vv[k];
        union { ushort s[8]; bf16x8 w; } u;
        u.w = *(const bf16x8*)(WdecT + (size_t)ff[k] * DIM + d0);
#pragma unroll
        for (int j = 0; j < 8; ++j)
            acc[j] = fmaf(v, bf16_to_f32(u.s[j]), acc[j]);
    }
    float* orow = out + (size_t)row * DIM + d0;
    float4 o0 = {acc[0], acc[1], acc[2], acc[3]};
    float4 o1 = {acc[4], acc[5], acc[6], acc[7]};
    *(float4*)(orow + 0) = o0;
    *(float4*)(orow + 4) = o1;
}

// ================= decode, FALLBACK path (chunked fp32, round-5) =============
__global__ __launch_bounds__(256) void transpose_kernel(
    const float* __restrict__ Wdec, float* __restrict__ Wt, int chunk_base)
{
    __shared__ float t[32][33];
    const int j0 = blockIdx.x * 32;
    const int d0 = blockIdx.y * 32;
    const int tx = threadIdx.x & 31;
    const int ty = threadIdx.x >> 5;
#pragma unroll
    for (int r = 0; r < 4; ++r)
        t[ty + 8 * r][tx] = Wdec[(size_t)(d0 + ty + 8 * r) * FDICT + chunk_base + j0 + tx];
    __syncthreads();
#pragma unroll
    for (int r = 0; r < 4; ++r)
        Wt[(size_t)(j0 + ty + 8 * r) * DIM + d0 + tx] = t[tx][ty + 8 * r];
}

__global__ __launch_bounds__(256) void init_out_kernel(
    float* __restrict__ out, const float* __restrict__ bdec)
{
    int i = blockIdx.x * 256 + threadIdx.x;
    out[i] = bdec[i & (DIM - 1)];
}

__global__ __launch_bounds__(256) void init_topk_kernel(
    float* __restrict__ run_val, int* __restrict__ run_idx)
{
    int i = blockIdx.x * 256 + threadIdx.x;
    if (i < B_ROWS * TOPC) { run_val[i] = 0.f; run_idx[i] = -1; }
}

__global__ __launch_bounds__(256) void decode_kernel(
    const float* __restrict__ Wt,
    const float* __restrict__ sel_val,
    const int* __restrict__ sel_idx,
    float* __restrict__ out,
    int chunk_base)
{
    const int row = blockIdx.x;
    const int tid = threadIdx.x;
    __shared__ float vv[KSEL];
    __shared__ int   ff[KSEL];
    if (tid < KSEL) {
        vv[tid] = sel_val[row * KSEL + tid];
        ff[tid] = sel_idx[row * KSEL + tid] - chunk_base;
    }
    __syncthreads();
    float acc[8] = {0.f, 0.f, 0.f, 0.f, 0.f, 0.f, 0.f, 0.f};
    for (int k = 0; k < KSEL; ++k) {
        int f = ff[k];
        if (0 <= f && f < FCHUNK) {
            float v = vv[k];
            const float* wrow = Wt + (size_t)f * DIM;
#pragma unroll
            for (int i = 0; i < 8; ++i)
                acc[i] += v * wrow[tid + 256 * i];
        }
    }
    float* orow = out + (size_t)row * DIM;
#pragma unroll
    for (int i = 0; i < 8; ++i)
        orow[tid + 256 * i] += acc[i];
}

// ======================= launch =======================
extern "C" void kernel_launch(void* const* d_in, const int* in_sizes, int n_in,
                              void* d_out, int out_size, void* d_ws, size_t ws_size,
                              hipStream_t stream)
{
    const float* x    = (const float*)d_in[0];
    const float* Wenc = (const float*)d_in[1];
    const float* benc = (const float*)d_in[2];
    const float* Wdec = (const float*)d_in[3];
    const float* bdec = (const float*)d_in[4];
    (void)in_sizes; (void)n_in; (void)out_size;
    float* out = (float*)d_out;

    char* ws = (char*)d_ws;
    const size_t SZ_BUF0  = (size_t)B_ROWS * FCHUNK * 4;     // 32 MB
    const size_t SZ_XBF   = (size_t)B_ROWS * DIM * 2;        //  8 MB
    const size_t SZ_RUNV  = (size_t)B_ROWS * TOPC * 4;
    const size_t SZ_SELV  = (size_t)B_ROWS * KSEL * 4;
    const size_t SZ_BIG   = (size_t)FDICT * DIM * 2;         // 128 MB (Wenc_bf16 / WdecT)

    size_t off = 0;
    float*  buf0    = (float*)(ws + off);  off += SZ_BUF0;
    ushort* x_bf16  = (ushort*)(ws + off); off += SZ_XBF;
    float*  run_val = (float*)(ws + off);  off += SZ_RUNV;
    int*    run_idx = (int*)(ws + off);    off += SZ_RUNV;
    float*  sel_val = (float*)(ws + off);  off += SZ_SELV;
    int*    sel_idx = (int*)(ws + off);    off += SZ_SELV;
    char*   big     = ws + off;            // full path: 128 MB region
    const bool full = (ws_size >= off + SZ_BIG);

    init_topk_kernel<<<(B_ROWS * TOPC + 255) / 256, 256, 0, stream>>>(run_val, run_idx);
    conv_bf16_kernel<<<(B_ROWS * DIM) / (256 * 8), 256, 0, stream>>>(x, x_bf16);

    if (full) {
        ushort* wenc_bf = (ushort*)big;
        conv_bf16_kernel<<<(int)(((size_t)FDICT * DIM) / (256 * 8)), 256, 0, stream>>>(
            Wenc, wenc_bf);
        for (int c = 0; c < NCHUNK; ++c) {
            enc_gemm_bt<<<dim3(FCHUNK / GN, B_ROWS / GM), 256, 0, stream>>>(
                x_bf16, wenc_bf + (size_t)c * FCHUNK * DIM, benc, buf0, c * FCHUNK);
            topk_merge_kernel<<<B_ROWS, 256, 0, stream>>>(buf0, run_val, run_idx, c * FCHUNK);
        }
        refine_np_kernel<<<B_ROWS / 2, 256, 0, stream>>>(x, Wenc, benc, run_idx, sel_val, sel_idx);

        ushort* WdecT = (ushort*)big;   // reuse: encode phase done
        transpose_wdec_bf16<<<dim3(FDICT / 64, DIM / 64), 256, 0, stream>>>(Wdec, WdecT);
        decode_full_kernel<<<B_ROWS, 256, 0, stream>>>(WdecT, sel_val, sel_idx, bdec, out);
    } else {
        ushort* wchunk = (ushort*)big;  // fallback: 16 MB chunk (fits old budget)
        for (int c = 0; c < NCHUNK; ++c) {
            conv_bf16_kernel<<<(int)(((size_t)FCHUNK * DIM) / (256 * 8)), 256, 0, stream>>>(
                Wenc + (size_t)c * FCHUNK * DIM, wchunk);
            enc_gemm_bt<<<dim3(FCHUNK / GN, B_ROWS / GM), 256, 0, stream>>>(
                x_bf16, wchunk, benc, buf0, c * FCHUNK);
            topk_merge_kernel<<<B_ROWS, 256, 0, stream>>>(buf0, run_val, run_idx, c * FCHUNK);
        }
        refine_np_kernel<<<B_ROWS / 2, 256, 0, stream>>>(x, Wenc, benc, run_idx, sel_val, sel_idx);

        init_out_kernel<<<(B_ROWS * DIM) / 256, 256, 0, stream>>>(out, bdec);
        for (int c = 0; c < NCHUNK; ++c) {
            transpose_kernel<<<dim3(FCHUNK / 32, DIM / 32), 256, 0, stream>>>(
                Wdec, buf0, c * FCHUNK);
            decode_kernel<<<B_ROWS, 256, 0, stream>>>(buf0, sel_val, sel_idx, out, c * FCHUNK);
        }
    }
}

// Round 7
// 1245.076 us; speedup vs baseline: 3.9588x; 1.2343x over previous
//
#include <hip/hip_runtime.h>
#include <stdint.h>

#define B_ROWS 2048
#define DIM    2048
#define FDICT  32768
#define KSEL   64
#define TOPC   96       // candidate list; refined bit-exactly vs np.einsum fp32
#define CAP    1536     // per-row candidate capacity (mean ~616 @ 2.35 sigma)
#define THRFAC 2.35f
#define WSAMPN (64 * DIM)   // Wenc sample count for sigma_w estimate

typedef __attribute__((ext_vector_type(8))) short bf16x8;
typedef __attribute__((ext_vector_type(4))) float f32x4;

__device__ __forceinline__ float bf16_to_f32(ushort u)
{
    return __uint_as_float(((uint32_t)u) << 16);
}

// ======================= init: zero counters =======================
__global__ __launch_bounds__(256) void zero_kernel(int* __restrict__ cand_cnt,
                                                   float* __restrict__ wsum)
{
    int i = blockIdx.x * 256 + threadIdx.x;
    if (i < B_ROWS) cand_cnt[i] = 0;
    if (i == 0) wsum[0] = 0.f;
}

// ======================= sigma_w estimate (sample 64 Wenc rows) ==============
__global__ __launch_bounds__(256) void wstat_kernel(
    const float* __restrict__ Wenc, float* __restrict__ wsum)
{
    __shared__ float red[256];
    const int tid = threadIdx.x;
    float s = 0.f;
    for (int i = blockIdx.x * 256 + tid; i < WSAMPN / 4; i += 8 * 256) {
        float4 w = ((const float4*)Wenc)[i];
        s += w.x * w.x + w.y * w.y + w.z * w.z + w.w * w.w;
    }
    red[tid] = s;
    __syncthreads();
    for (int o = 128; o > 0; o >>= 1) {
        if (tid < o) red[tid] += red[tid + o];
        __syncthreads();
    }
    if (tid == 0) atomicAdd(wsum, red[0]);
}

// ======================= per-row threshold: T = f * sigma_w * ||x_row|| ======
__global__ __launch_bounds__(256) void rownorm_kernel(
    const float* __restrict__ x, const float* __restrict__ wsum,
    float* __restrict__ T)
{
    __shared__ float red[256];
    const int row = blockIdx.x;
    const int tid = threadIdx.x;
    const float4* xr = (const float4*)(x + (size_t)row * DIM);
    float s = 0.f;
#pragma unroll
    for (int u = 0; u < 2; ++u) {
        float4 v = xr[tid + u * 256];
        s += v.x * v.x + v.y * v.y + v.z * v.z + v.w * v.w;
    }
    red[tid] = s;
    __syncthreads();
    for (int o = 128; o > 0; o >>= 1) {
        if (tid < o) red[tid] += red[tid + o];
        __syncthreads();
    }
    if (tid == 0)
        T[row] = THRFAC * sqrtf(wsum[0] / (float)WSAMPN) * sqrtf(red[0]);
}

// -------- fp32 -> bf16 (RNE) streaming convert --------
__global__ __launch_bounds__(256) void conv_bf16_kernel(
    const float* __restrict__ src, ushort* __restrict__ dst)
{
    const size_t i = ((size_t)blockIdx.x * 256 + threadIdx.x) * 8;
    float4 u = *(const float4*)(src + i);
    float4 v = *(const float4*)(src + i + 4);
    union { ushort s[8]; bf16x8 w; } o;
    float t[8] = {u.x, u.y, u.z, u.w, v.x, v.y, v.z, v.w};
#pragma unroll
    for (int j = 0; j < 8; ++j) {
        union { __bf16 h; ushort s; } cv;
        cv.h = (__bf16)t[j];
        o.s[j] = cv.s;
    }
    *(bf16x8*)(dst + i) = o.w;
}

// ====== encode GEMM (bf16 MFMA, m97 structure) + threshold candidate emit ====
#define GM 128
#define GN 128
#define GK 64

__device__ __forceinline__ void gload_lds16(const void* g, void* l)
{
    __builtin_amdgcn_global_load_lds(
        (const __attribute__((address_space(1))) void*)(uintptr_t)g,
        (__attribute__((address_space(3))) void*)(uint32_t)(uintptr_t)l,
        16, 0, 0);
}

__global__ __launch_bounds__(256) void enc_gemm_cand(
    const ushort* __restrict__ A,    // x_bf16    [B_ROWS][DIM]
    const ushort* __restrict__ Bw,   // Wenc_bf16 [FDICT][DIM]
    const float* __restrict__ benc,
    const float* __restrict__ T,     // [B_ROWS] per-row threshold
    float* __restrict__ cand_val,    // [B_ROWS][CAP]
    int* __restrict__ cand_idx,      // [B_ROWS][CAP]
    int* __restrict__ cand_cnt)      // [B_ROWS]
{
    __shared__ __align__(16) ushort As[GM * GK];
    __shared__ __align__(16) ushort Bs[GN * GK];
    __shared__ float Ts[GM];

    const int tid  = threadIdx.x;
    const int lane = tid & 63;
    const int wv   = tid >> 6;
    const int wr   = wv >> 1, wc = wv & 1;
    const int lr   = lane & 15, lg = lane >> 4;
    const int row0 = blockIdx.x * GM;   // grid.x = 16 row-blocks (fast dim)
    const int col0 = blockIdx.y * GN;   // grid.y = 256 col-blocks

    if (tid < GM) Ts[tid] = T[row0 + tid];

    const ushort* aSrc = A  + (size_t)row0 * DIM;
    const ushort* bSrc = Bw + (size_t)col0 * DIM;

    const int srow = (lane >> 3);
    const int scol = (lane & 7) * 8;

    f32x4 acc[4][4] = {};

    for (int kt = 0; kt < DIM / GK; ++kt) {
        const int k0 = kt * GK;
        __syncthreads();
#pragma unroll
        for (int i = 0; i < 4; ++i) {
            const int g = wv * 4 + i;
            const int r = g * 8 + srow;
            gload_lds16(aSrc + (size_t)r * DIM + k0 + scol, (char*)As + g * 1024);
            gload_lds16(bSrc + (size_t)r * DIM + k0 + scol, (char*)Bs + g * 1024);
        }
        __syncthreads();

        bf16x8 af[2][4], bfr[2][4];
#pragma unroll
        for (int kk = 0; kk < 2; ++kk) {
#pragma unroll
            for (int mi = 0; mi < 4; ++mi)
                af[kk][mi] = *(const bf16x8*)(As + (wr * 64 + mi * 16 + lr) * GK + kk * 32 + lg * 8);
#pragma unroll
            for (int ni = 0; ni < 4; ++ni)
                bfr[kk][ni] = *(const bf16x8*)(Bs + (wc * 64 + ni * 16 + lr) * GK + kk * 32 + lg * 8);
        }
#pragma unroll
        for (int kk = 0; kk < 2; ++kk)
#pragma unroll
            for (int mi = 0; mi < 4; ++mi)
#pragma unroll
                for (int ni = 0; ni < 4; ++ni)
                    acc[mi][ni] = __builtin_amdgcn_mfma_f32_16x16x32_bf16(
                        af[kk][mi], bfr[kk][ni], acc[mi][ni], 0, 0, 0);
    }

    float bias[4];
#pragma unroll
    for (int ni = 0; ni < 4; ++ni)
        bias[ni] = benc[col0 + wc * 64 + ni * 16 + lr];

    // C/D layout (verified r4): col = lane&15, row = (lane>>4)*4 + reg
#pragma unroll
    for (int mi = 0; mi < 4; ++mi) {
#pragma unroll
        for (int r = 0; r < 4; ++r) {
            const int rloc = wr * 64 + mi * 16 + lg * 4 + r;
            const float t = Ts[rloc];
#pragma unroll
            for (int ni = 0; ni < 4; ++ni) {
                const float v = acc[mi][ni][r] + bias[ni];
                if (fabsf(v) >= t) {
                    const int grow = row0 + rloc;
                    const int gcol = col0 + wc * 64 + ni * 16 + lr;
                    int pos = atomicAdd(&cand_cnt[grow], 1);
                    if (pos < CAP) {
                        cand_val[(size_t)grow * CAP + pos] = v;
                        cand_idx[(size_t)grow * CAP + pos] = gcol;
                    }
                }
            }
        }
    }
}

// ============ exact radix select: candidates -> top-TOPC indices =============
__global__ __launch_bounds__(256) void select_kernel(
    const float* __restrict__ cand_val,
    const int* __restrict__ cand_idx,
    const int* __restrict__ cand_cnt,
    int* __restrict__ run_idx)
{
    const int row = blockIdx.x;
    const int tid = threadIdx.x;

    __shared__ uint32_t ua[CAP];
    __shared__ int      si[CAP];
    __shared__ int      hist[256];
    __shared__ uint32_t sh_prefix;
    __shared__ int      sh_cgt, c_out, c_eq;

    int cnt = cand_cnt[row];
    if (cnt > CAP) cnt = CAP;

    for (int j = tid; j < cnt; j += 256) {
        ua[j] = __float_as_uint(cand_val[(size_t)row * CAP + j]) & 0x7fffffffu;
        si[j] = cand_idx[(size_t)row * CAP + j];
    }
    if (tid == 0) { sh_prefix = 0u; sh_cgt = 0; c_out = 0; c_eq = 0; }
    __syncthreads();

    if (cnt <= TOPC) {
        if (tid < TOPC) run_idx[(size_t)row * TOPC + tid] = (tid < cnt) ? si[tid] : -1;
        return;
    }

    for (int p = 3; p >= 0; --p) {
        hist[tid] = 0;
        __syncthreads();
        const uint32_t mask = (p == 3) ? 0u : (0xffffffffu << ((p + 1) * 8));
        const uint32_t pref = sh_prefix;
        for (int j = tid; j < cnt; j += 256) {
            uint32_t u = ua[j];
            if ((u & mask) == pref)
                atomicAdd(&hist[(u >> (p * 8)) & 255], 1);
        }
        __syncthreads();
        if (tid == 0) {
            int cum = sh_cgt;
            int chosen = 0;
            for (int b = 255; b >= 0; --b) {
                int c = hist[b];
                if (cum + c >= TOPC) { chosen = b; break; }
                cum += c;
            }
            sh_prefix = sh_prefix | ((uint32_t)chosen << (p * 8));
            sh_cgt = cum;
        }
        __syncthreads();
    }

    const uint32_t uth = sh_prefix;
    for (int j = tid; j < cnt; j += 256) {
        if (ua[j] > uth) {
            int pos = atomicAdd(&c_out, 1);
            run_idx[(size_t)row * TOPC + pos] = si[j];
        }
    }
    __syncthreads();
    const int base = c_out;
    for (int j = tid; j < cnt; j += 256) {
        if (ua[j] == uth) {
            int e = atomicAdd(&c_eq, 1);
            int slot = base + e;
            if (slot < TOPC) run_idx[(size_t)row * TOPC + slot] = si[j];
        }
    }
}

// ============ np.einsum-bit-exact refinement of TOPC candidates ==============
// numpy fp32 SSE chain: 4 accumulators over d%4 ascending, round(mul) then
// round(add) (no FMA), combined (a0+a2)+(a1+a3), then + b_enc.
// Ping-pong double-buffered loads (2x8 float4 in flight) for MLP.
__global__ __launch_bounds__(256) void refine_np_kernel(
    const float* __restrict__ x,
    const float* __restrict__ Wenc,
    const float* __restrict__ benc,
    const int* __restrict__ run_idx,
    float* __restrict__ sel_val,
    int* __restrict__ sel_idx)
{
    const int half = threadIdx.x >> 7;      // row within block (0..1)
    const int cid  = threadIdx.x & 127;     // candidate id (<TOPC active)
    const int row  = blockIdx.x * 2 + half;

    __shared__ __align__(16) float xs[2][DIM];
    __shared__ float cval[2][TOPC];
    __shared__ int   cidx[2][TOPC];

    {
        const float4* src = (const float4*)(x + (size_t)blockIdx.x * 2 * DIM);
        for (int i = threadIdx.x; i < 2 * DIM / 4; i += 256)
            ((float4*)xs)[i] = src[i];
    }
    if (cid < TOPC) cidx[half][cid] = run_idx[(size_t)row * TOPC + cid];
    __syncthreads();

    if (cid < TOPC) {
        const int f = cidx[half][cid];
        if (f >= 0) {
            const float4* w4 = (const float4*)(Wenc + (size_t)f * DIM);
            const float4* x4 = (const float4*)xs[half];
            float a0 = 0.f, a1 = 0.f, a2 = 0.f, a3 = 0.f;
            float4 pa[8], pb[8];
#pragma unroll
            for (int u = 0; u < 8; ++u) pa[u] = w4[u];
            for (int t0 = 0; t0 < DIM / 4; t0 += 16) {
#pragma unroll
                for (int u = 0; u < 8; ++u) pb[u] = w4[t0 + 8 + u];
#pragma unroll
                for (int u = 0; u < 8; ++u) {
                    float4 xv = x4[t0 + u];
                    a0 = __fadd_rn(a0, __fmul_rn(xv.x, pa[u].x));
                    a1 = __fadd_rn(a1, __fmul_rn(xv.y, pa[u].y));
                    a2 = __fadd_rn(a2, __fmul_rn(xv.z, pa[u].z));
                    a3 = __fadd_rn(a3, __fmul_rn(xv.w, pa[u].w));
                }
                if (t0 + 16 < DIM / 4) {
#pragma unroll
                    for (int u = 0; u < 8; ++u) pa[u] = w4[t0 + 16 + u];
                }
#pragma unroll
                for (int u = 0; u < 8; ++u) {
                    float4 xv = x4[t0 + 8 + u];
                    a0 = __fadd_rn(a0, __fmul_rn(xv.x, pb[u].x));
                    a1 = __fadd_rn(a1, __fmul_rn(xv.y, pb[u].y));
                    a2 = __fadd_rn(a2, __fmul_rn(xv.z, pb[u].z));
                    a3 = __fadd_rn(a3, __fmul_rn(xv.w, pb[u].w));
                }
            }
            float v = __fadd_rn(__fadd_rn(a0, a2), __fadd_rn(a1, a3));
            cval[half][cid] = __fadd_rn(v, benc[f]);
        } else {
            cval[half][cid] = 0.f;
        }
    }
    __syncthreads();

    if (cid < TOPC) {
        const int f = cidx[half][cid];
        if (f >= 0) {
            const uint32_t av = __float_as_uint(cval[half][cid]) & 0x7fffffffu;
            int rank = 0;
            for (int u = 0; u < TOPC; ++u) {
                if (u == cid) continue;
                int fu = cidx[half][u];
                if (fu < 0) continue;
                uint32_t au = __float_as_uint(cval[half][u]) & 0x7fffffffu;
                if (au > av || (au == av && fu < f)) ++rank;
            }
            if (rank < KSEL) {
                sel_val[(size_t)row * KSEL + rank] = cval[half][cid];
                sel_idx[(size_t)row * KSEL + rank] = f;
            }
        }
    }
}

// ================= decode: Wdec -> bf16 [F][D], one-pass gather ==============
__global__ __launch_bounds__(256) void transpose_wdec_bf16(
    const float* __restrict__ Wdec,   // [DIM][FDICT]
    ushort* __restrict__ WdecT)       // [FDICT][DIM] bf16
{
    __shared__ float t[64][65];
    const int f0 = blockIdx.x * 64;
    const int d0 = blockIdx.y * 64;
    const int tx = threadIdx.x & 63;
    const int ty = threadIdx.x >> 6;  // 0..3
#pragma unroll
    for (int r = 0; r < 16; ++r)
        t[ty * 16 + r][tx] = Wdec[(size_t)(d0 + ty * 16 + r) * FDICT + f0 + tx];
    __syncthreads();
#pragma unroll
    for (int r = 0; r < 16; ++r) {
        union { __bf16 h; ushort s; } cv;
        cv.h = (__bf16)t[tx][ty * 16 + r];
        WdecT[(size_t)(f0 + ty * 16 + r) * DIM + d0 + tx] = cv.s;
    }
}

__global__ __launch_bounds__(256) void decode_full_kernel(
    const ushort* __restrict__ WdecT,   // [FDICT][DIM] bf16
    const float* __restrict__ sel_val,
    const int* __restrict__ sel_idx,
    const float* __restrict__ bdec,
    float* __restrict__ out)
{
    const int row = blockIdx.x;
    const int tid = threadIdx.x;
    __shared__ float vv[KSEL];
    __shared__ int   ff[KSEL];
    if (tid < KSEL) {
        vv[tid] = sel_val[row * KSEL + tid];
        ff[tid] = sel_idx[row * KSEL + tid];
    }
    __syncthreads();
    const int d0 = tid * 8;
    float acc[8];
    {
        float4 b0 = *(const float4*)(bdec + d0);
        float4 b1 = *(const float4*)(bdec + d0 + 4);
        acc[0] = b0.x; acc[1] = b0.y; acc[2] = b0.z; acc[3] = b0.w;
        acc[4] = b1.x; acc[5] = b1.y; acc[6] = b1.z; acc[7] = b1.w;
    }
    for (int k = 0; k < KSEL; ++k) {
        const float v = vv[k];
        union { ushort s[8]; bf16x8 w; } u;
        u.w = *(const bf16x8*)(WdecT + (size_t)ff[k] * DIM + d0);
#pragma unroll
        for (int j = 0; j < 8; ++j)
            acc[j] = fmaf(v, bf16_to_f32(u.s[j]), acc[j]);
    }
    float* orow = out + (size_t)row * DIM + d0;
    float4 o0 = {acc[0], acc[1], acc[2], acc[3]};
    float4 o1 = {acc[4], acc[5], acc[6], acc[7]};
    *(float4*)(orow + 0) = o0;
    *(float4*)(orow + 4) = o1;
}

// ======================= launch =======================
extern "C" void kernel_launch(void* const* d_in, const int* in_sizes, int n_in,
                              void* d_out, int out_size, void* d_ws, size_t ws_size,
                              hipStream_t stream)
{
    const float* x    = (const float*)d_in[0];
    const float* Wenc = (const float*)d_in[1];
    const float* benc = (const float*)d_in[2];
    const float* Wdec = (const float*)d_in[3];
    const float* bdec = (const float*)d_in[4];
    (void)in_sizes; (void)n_in; (void)out_size; (void)ws_size;
    float* out = (float*)d_out;

    char* ws = (char*)d_ws;
    size_t off = 0;
    float*  cand_val = (float*)(ws + off);  off += (size_t)B_ROWS * CAP * 4;   // 12.6 MB
    int*    cand_idx = (int*)(ws + off);    off += (size_t)B_ROWS * CAP * 4;   // 12.6 MB
    int*    cand_cnt = (int*)(ws + off);    off += (size_t)B_ROWS * 4;
    float*  Tthr     = (float*)(ws + off);  off += (size_t)B_ROWS * 4;
    float*  wsum     = (float*)(ws + off);  off += 256;
    ushort* x_bf16   = (ushort*)(ws + off); off += (size_t)B_ROWS * DIM * 2;   // 8 MB
    int*    run_idx  = (int*)(ws + off);    off += (size_t)B_ROWS * TOPC * 4;
    float*  sel_val  = (float*)(ws + off);  off += (size_t)B_ROWS * KSEL * 4;
    int*    sel_idx  = (int*)(ws + off);    off += (size_t)B_ROWS * KSEL * 4;
    char*   big      = ws + off;            // 128 MB: wenc_bf16, then WdecT

    zero_kernel<<<(B_ROWS + 255) / 256, 256, 0, stream>>>(cand_cnt, wsum);
    wstat_kernel<<<8, 256, 0, stream>>>(Wenc, wsum);
    rownorm_kernel<<<B_ROWS, 256, 0, stream>>>(x, wsum, Tthr);
    conv_bf16_kernel<<<(B_ROWS * DIM) / (256 * 8), 256, 0, stream>>>(x, x_bf16);

    ushort* wenc_bf = (ushort*)big;
    conv_bf16_kernel<<<(int)(((size_t)FDICT * DIM) / (256 * 8)), 256, 0, stream>>>(
        Wenc, wenc_bf);
    enc_gemm_cand<<<dim3(B_ROWS / GM, FDICT / GN), 256, 0, stream>>>(
        x_bf16, wenc_bf, benc, Tthr, cand_val, cand_idx, cand_cnt);

    select_kernel<<<B_ROWS, 256, 0, stream>>>(cand_val, cand_idx, cand_cnt, run_idx);
    refine_np_kernel<<<B_ROWS / 2, 256, 0, stream>>>(x, Wenc, benc, run_idx, sel_val, sel_idx);

    ushort* WdecT = (ushort*)big;   // reuse: encode phase done
    transpose_wdec_bf16<<<dim3(FDICT / 64, DIM / 64), 256, 0, stream>>>(Wdec, WdecT);
    decode_full_kernel<<<B_ROWS, 256, 0, stream>>>(WdecT, sel_val, sel_idx, bdec, out);
}

// Round 8
// 1110.410 us; speedup vs baseline: 4.4389x; 1.1213x over previous
//
#include <hip/hip_runtime.h>
#include <stdint.h>

#define B_ROWS 2048
#define DIM    2048
#define FDICT  32768
#define KSEL   64
#define TOPC   96       // candidate list; refined bit-exactly vs np.einsum fp32
#define CAP    1536     // per-row candidate capacity (mean ~616 @ 2.35 sigma)
#define THRFAC 2.35f
#define WSAMPN (64 * DIM)   // Wenc sample count for sigma_w estimate

typedef __attribute__((ext_vector_type(8))) short bf16x8;
typedef __attribute__((ext_vector_type(4))) float f32x4;

__device__ __forceinline__ float bf16_to_f32(ushort u)
{
    return __uint_as_float(((uint32_t)u) << 16);
}

// ======================= init: zero counters =======================
__global__ __launch_bounds__(256) void zero_kernel(int* __restrict__ cand_cnt,
                                                   float* __restrict__ wsum)
{
    int i = blockIdx.x * 256 + threadIdx.x;
    if (i < B_ROWS) cand_cnt[i] = 0;
    if (i == 0) wsum[0] = 0.f;
}

// ======================= sigma_w estimate (sample 64 Wenc rows) ==============
__global__ __launch_bounds__(256) void wstat_kernel(
    const float* __restrict__ Wenc, float* __restrict__ wsum)
{
    __shared__ float red[256];
    const int tid = threadIdx.x;
    float s = 0.f;
    for (int i = blockIdx.x * 256 + tid; i < WSAMPN / 4; i += 8 * 256) {
        float4 w = ((const float4*)Wenc)[i];
        s += w.x * w.x + w.y * w.y + w.z * w.z + w.w * w.w;
    }
    red[tid] = s;
    __syncthreads();
    for (int o = 128; o > 0; o >>= 1) {
        if (tid < o) red[tid] += red[tid + o];
        __syncthreads();
    }
    if (tid == 0) atomicAdd(wsum, red[0]);
}

// ======================= per-row threshold: T = f * sigma_w * ||x_row|| ======
__global__ __launch_bounds__(256) void rownorm_kernel(
    const float* __restrict__ x, const float* __restrict__ wsum,
    float* __restrict__ T)
{
    __shared__ float red[256];
    const int row = blockIdx.x;
    const int tid = threadIdx.x;
    const float4* xr = (const float4*)(x + (size_t)row * DIM);
    float s = 0.f;
#pragma unroll
    for (int u = 0; u < 2; ++u) {
        float4 v = xr[tid + u * 256];
        s += v.x * v.x + v.y * v.y + v.z * v.z + v.w * v.w;
    }
    red[tid] = s;
    __syncthreads();
    for (int o = 128; o > 0; o >>= 1) {
        if (tid < o) red[tid] += red[tid + o];
        __syncthreads();
    }
    if (tid == 0)
        T[row] = THRFAC * sqrtf(wsum[0] / (float)WSAMPN) * sqrtf(red[0]);
}

// -------- fp32 -> bf16 (RNE) streaming convert --------
__global__ __launch_bounds__(256) void conv_bf16_kernel(
    const float* __restrict__ src, ushort* __restrict__ dst)
{
    const size_t i = ((size_t)blockIdx.x * 256 + threadIdx.x) * 8;
    float4 u = *(const float4*)(src + i);
    float4 v = *(const float4*)(src + i + 4);
    union { ushort s[8]; bf16x8 w; } o;
    float t[8] = {u.x, u.y, u.z, u.w, v.x, v.y, v.z, v.w};
#pragma unroll
    for (int j = 0; j < 8; ++j) {
        union { __bf16 h; ushort s; } cv;
        cv.h = (__bf16)t[j];
        o.s[j] = cv.s;
    }
    *(bf16x8*)(dst + i) = o.w;
}

// ====== encode GEMM (bf16 MFMA, m97 structure + T2 XOR swizzle) ==============
// LDS tile rows are 128B stride -> naive ds_read_b128 is a 16-way bank
// conflict (1.0e8 counted in r7). Fix per rule #21: global_load_lds writes
// linearly, so pre-swizzle the per-lane GLOBAL source column and apply the
// same XOR on the read side. LDS[row][blk8] holds global block blk8^(row&7).
#define GM 128
#define GN 128
#define GK 64

__device__ __forceinline__ void gload_lds16(const void* g, void* l)
{
    __builtin_amdgcn_global_load_lds(
        (const __attribute__((address_space(1))) void*)(uintptr_t)g,
        (__attribute__((address_space(3))) void*)(uint32_t)(uintptr_t)l,
        16, 0, 0);
}

__global__ __launch_bounds__(256) void enc_gemm_cand(
    const ushort* __restrict__ A,    // x_bf16    [B_ROWS][DIM]
    const ushort* __restrict__ Bw,   // Wenc_bf16 [FDICT][DIM]
    const float* __restrict__ benc,
    const float* __restrict__ T,     // [B_ROWS] per-row threshold
    float* __restrict__ cand_val,    // [B_ROWS][CAP]
    int* __restrict__ cand_idx,      // [B_ROWS][CAP]
    int* __restrict__ cand_cnt)      // [B_ROWS]
{
    __shared__ __align__(16) ushort As[GM * GK];
    __shared__ __align__(16) ushort Bs[GN * GK];
    __shared__ float Ts[GM];

    const int tid  = threadIdx.x;
    const int lane = tid & 63;
    const int wv   = tid >> 6;
    const int wr   = wv >> 1, wc = wv & 1;
    const int lr   = lane & 15, lg = lane >> 4;
    const int row0 = blockIdx.x * GM;   // grid.x = 16 row-blocks (fast dim)
    const int col0 = blockIdx.y * GN;   // grid.y = 256 col-blocks

    if (tid < GM) Ts[tid] = T[row0 + tid];

    const ushort* aSrc = A  + (size_t)row0 * DIM;
    const ushort* bSrc = Bw + (size_t)col0 * DIM;

    const int srow   = (lane >> 3);                    // row within 8-row group
    const int scolsw = ((lane & 7) ^ srow) * 8;        // PRE-SWIZZLED source col

    f32x4 acc[4][4] = {};

    for (int kt = 0; kt < DIM / GK; ++kt) {
        const int k0 = kt * GK;
        __syncthreads();
#pragma unroll
        for (int i = 0; i < 4; ++i) {
            const int g = wv * 4 + i;
            const int r = g * 8 + srow;
            gload_lds16(aSrc + (size_t)r * DIM + k0 + scolsw, (char*)As + g * 1024);
            gload_lds16(bSrc + (size_t)r * DIM + k0 + scolsw, (char*)Bs + g * 1024);
        }
        __syncthreads();

        bf16x8 af[2][4], bfr[2][4];
#pragma unroll
        for (int kk = 0; kk < 2; ++kk) {
            const int csw = (kk * 32 + lg * 8) ^ ((lr & 7) << 3);  // swizzled read col
#pragma unroll
            for (int mi = 0; mi < 4; ++mi)
                af[kk][mi] = *(const bf16x8*)(As + (wr * 64 + mi * 16 + lr) * GK + csw);
#pragma unroll
            for (int ni = 0; ni < 4; ++ni)
                bfr[kk][ni] = *(const bf16x8*)(Bs + (wc * 64 + ni * 16 + lr) * GK + csw);
        }
#pragma unroll
        for (int kk = 0; kk < 2; ++kk)
#pragma unroll
            for (int mi = 0; mi < 4; ++mi)
#pragma unroll
                for (int ni = 0; ni < 4; ++ni)
                    acc[mi][ni] = __builtin_amdgcn_mfma_f32_16x16x32_bf16(
                        af[kk][mi], bfr[kk][ni], acc[mi][ni], 0, 0, 0);
    }

    float bias[4];
#pragma unroll
    for (int ni = 0; ni < 4; ++ni)
        bias[ni] = benc[col0 + wc * 64 + ni * 16 + lr];

    // C/D layout (verified r4): col = lane&15, row = (lane>>4)*4 + reg
#pragma unroll
    for (int mi = 0; mi < 4; ++mi) {
#pragma unroll
        for (int r = 0; r < 4; ++r) {
            const int rloc = wr * 64 + mi * 16 + lg * 4 + r;
            const float t = Ts[rloc];
#pragma unroll
            for (int ni = 0; ni < 4; ++ni) {
                const float v = acc[mi][ni][r] + bias[ni];
                if (fabsf(v) >= t) {
                    const int grow = row0 + rloc;
                    const int gcol = col0 + wc * 64 + ni * 16 + lr;
                    int pos = atomicAdd(&cand_cnt[grow], 1);
                    if (pos < CAP) {
                        cand_val[(size_t)grow * CAP + pos] = v;
                        cand_idx[(size_t)grow * CAP + pos] = gcol;
                    }
                }
            }
        }
    }
}

// ============ exact radix select: candidates -> top-TOPC indices =============
__global__ __launch_bounds__(256) void select_kernel(
    const float* __restrict__ cand_val,
    const int* __restrict__ cand_idx,
    const int* __restrict__ cand_cnt,
    int* __restrict__ run_idx)
{
    const int row = blockIdx.x;
    const int tid = threadIdx.x;

    __shared__ uint32_t ua[CAP];
    __shared__ int      si[CAP];
    __shared__ int      hist[256];
    __shared__ uint32_t sh_prefix;
    __shared__ int      sh_cgt, c_out, c_eq;

    int cnt = cand_cnt[row];
    if (cnt > CAP) cnt = CAP;

    for (int j = tid; j < cnt; j += 256) {
        ua[j] = __float_as_uint(cand_val[(size_t)row * CAP + j]) & 0x7fffffffu;
        si[j] = cand_idx[(size_t)row * CAP + j];
    }
    if (tid == 0) { sh_prefix = 0u; sh_cgt = 0; c_out = 0; c_eq = 0; }
    __syncthreads();

    if (cnt <= TOPC) {
        if (tid < TOPC) run_idx[(size_t)row * TOPC + tid] = (tid < cnt) ? si[tid] : -1;
        return;
    }

    for (int p = 3; p >= 0; --p) {
        hist[tid] = 0;
        __syncthreads();
        const uint32_t mask = (p == 3) ? 0u : (0xffffffffu << ((p + 1) * 8));
        const uint32_t pref = sh_prefix;
        for (int j = tid; j < cnt; j += 256) {
            uint32_t u = ua[j];
            if ((u & mask) == pref)
                atomicAdd(&hist[(u >> (p * 8)) & 255], 1);
        }
        __syncthreads();
        if (tid == 0) {
            int cum = sh_cgt;
            int chosen = 0;
            for (int b = 255; b >= 0; --b) {
                int c = hist[b];
                if (cum + c >= TOPC) { chosen = b; break; }
                cum += c;
            }
            sh_prefix = sh_prefix | ((uint32_t)chosen << (p * 8));
            sh_cgt = cum;
        }
        __syncthreads();
    }

    const uint32_t uth = sh_prefix;
    for (int j = tid; j < cnt; j += 256) {
        if (ua[j] > uth) {
            int pos = atomicAdd(&c_out, 1);
            run_idx[(size_t)row * TOPC + pos] = si[j];
        }
    }
    __syncthreads();
    const int base = c_out;
    for (int j = tid; j < cnt; j += 256) {
        if (ua[j] == uth) {
            int e = atomicAdd(&c_eq, 1);
            int slot = base + e;
            if (slot < TOPC) run_idx[(size_t)row * TOPC + slot] = si[j];
        }
    }
}

// ============ np.einsum-bit-exact refinement of TOPC candidates ==============
// numpy fp32 SSE chain: 4 accumulators over d%4 ascending, round(mul) then
// round(add) (no FMA), combined (a0+a2)+(a1+a3), then + b_enc.
// Ping-pong double-buffered loads (2x8 float4 in flight) for MLP.
__global__ __launch_bounds__(256) void refine_np_kernel(
    const float* __restrict__ x,
    const float* __restrict__ Wenc,
    const float* __restrict__ benc,
    const int* __restrict__ run_idx,
    float* __restrict__ sel_val,
    int* __restrict__ sel_idx)
{
    const int half = threadIdx.x >> 7;      // row within block (0..1)
    const int cid  = threadIdx.x & 127;     // candidate id (<TOPC active)
    const int row  = blockIdx.x * 2 + half;

    __shared__ __align__(16) float xs[2][DIM];
    __shared__ float cval[2][TOPC];
    __shared__ int   cidx[2][TOPC];

    {
        const float4* src = (const float4*)(x + (size_t)blockIdx.x * 2 * DIM);
        for (int i = threadIdx.x; i < 2 * DIM / 4; i += 256)
            ((float4*)xs)[i] = src[i];
    }
    if (cid < TOPC) cidx[half][cid] = run_idx[(size_t)row * TOPC + cid];
    __syncthreads();

    if (cid < TOPC) {
        const int f = cidx[half][cid];
        if (f >= 0) {
            const float4* w4 = (const float4*)(Wenc + (size_t)f * DIM);
            const float4* x4 = (const float4*)xs[half];
            float a0 = 0.f, a1 = 0.f, a2 = 0.f, a3 = 0.f;
            float4 pa[8], pb[8];
#pragma unroll
            for (int u = 0; u < 8; ++u) pa[u] = w4[u];
            for (int t0 = 0; t0 < DIM / 4; t0 += 16) {
#pragma unroll
                for (int u = 0; u < 8; ++u) pb[u] = w4[t0 + 8 + u];
#pragma unroll
                for (int u = 0; u < 8; ++u) {
                    float4 xv = x4[t0 + u];
                    a0 = __fadd_rn(a0, __fmul_rn(xv.x, pa[u].x));
                    a1 = __fadd_rn(a1, __fmul_rn(xv.y, pa[u].y));
                    a2 = __fadd_rn(a2, __fmul_rn(xv.z, pa[u].z));
                    a3 = __fadd_rn(a3, __fmul_rn(xv.w, pa[u].w));
                }
                if (t0 + 16 < DIM / 4) {
#pragma unroll
                    for (int u = 0; u < 8; ++u) pa[u] = w4[t0 + 16 + u];
                }
#pragma unroll
                for (int u = 0; u < 8; ++u) {
                    float4 xv = x4[t0 + 8 + u];
                    a0 = __fadd_rn(a0, __fmul_rn(xv.x, pb[u].x));
                    a1 = __fadd_rn(a1, __fmul_rn(xv.y, pb[u].y));
                    a2 = __fadd_rn(a2, __fmul_rn(xv.z, pb[u].z));
                    a3 = __fadd_rn(a3, __fmul_rn(xv.w, pb[u].w));
                }
            }
            float v = __fadd_rn(__fadd_rn(a0, a2), __fadd_rn(a1, a3));
            cval[half][cid] = __fadd_rn(v, benc[f]);
        } else {
            cval[half][cid] = 0.f;
        }
    }
    __syncthreads();

    if (cid < TOPC) {
        const int f = cidx[half][cid];
        if (f >= 0) {
            const uint32_t av = __float_as_uint(cval[half][cid]) & 0x7fffffffu;
            int rank = 0;
            for (int u = 0; u < TOPC; ++u) {
                if (u == cid) continue;
                int fu = cidx[half][u];
                if (fu < 0) continue;
                uint32_t au = __float_as_uint(cval[half][u]) & 0x7fffffffu;
                if (au > av || (au == av && fu < f)) ++rank;
            }
            if (rank < KSEL) {
                sel_val[(size_t)row * KSEL + rank] = cval[half][cid];
                sel_idx[(size_t)row * KSEL + rank] = f;
            }
        }
    }
}

// ================= decode: Wdec -> bf16 [F][D], one-pass gather ==============
__global__ __launch_bounds__(256) void transpose_wdec_bf16(
    const float* __restrict__ Wdec,   // [DIM][FDICT]
    ushort* __restrict__ WdecT)       // [FDICT][DIM] bf16
{
    __shared__ float t[64][65];
    const int f0 = blockIdx.x * 64;
    const int d0 = blockIdx.y * 64;
    const int tx = threadIdx.x & 63;
    const int ty = threadIdx.x >> 6;  // 0..3
#pragma unroll
    for (int r = 0; r < 16; ++r)
        t[ty * 16 + r][tx] = Wdec[(size_t)(d0 + ty * 16 + r) * FDICT + f0 + tx];
    __syncthreads();
#pragma unroll
    for (int r = 0; r < 16; ++r) {
        union { __bf16 h; ushort s; } cv;
        cv.h = (__bf16)t[tx][ty * 16 + r];
        WdecT[(size_t)(f0 + ty * 16 + r) * DIM + d0 + tx] = cv.s;
    }
}

__global__ __launch_bounds__(256) void decode_full_kernel(
    const ushort* __restrict__ WdecT,   // [FDICT][DIM] bf16
    const float* __restrict__ sel_val,
    const int* __restrict__ sel_idx,
    const float* __restrict__ bdec,
    float* __restrict__ out)
{
    const int row = blockIdx.x;
    const int tid = threadIdx.x;
    __shared__ float vv[KSEL];
    __shared__ int   ff[KSEL];
    if (tid < KSEL) {
        vv[tid] = sel_val[row * KSEL + tid];
        ff[tid] = sel_idx[row * KSEL + tid];
    }
    __syncthreads();
    const int d0 = tid * 8;
    float acc[8];
    {
        float4 b0 = *(const float4*)(bdec + d0);
        float4 b1 = *(const float4*)(bdec + d0 + 4);
        acc[0] = b0.x; acc[1] = b0.y; acc[2] = b0.z; acc[3] = b0.w;
        acc[4] = b1.x; acc[5] = b1.y; acc[6] = b1.z; acc[7] = b1.w;
    }
    for (int k = 0; k < KSEL; ++k) {
        const float v = vv[k];
        union { ushort s[8]; bf16x8 w; } u;
        u.w = *(const bf16x8*)(WdecT + (size_t)ff[k] * DIM + d0);
#pragma unroll
        for (int j = 0; j < 8; ++j)
            acc[j] = fmaf(v, bf16_to_f32(u.s[j]), acc[j]);
    }
    float* orow = out + (size_t)row * DIM + d0;
    float4 o0 = {acc[0], acc[1], acc[2], acc[3]};
    float4 o1 = {acc[4], acc[5], acc[6], acc[7]};
    *(float4*)(orow + 0) = o0;
    *(float4*)(orow + 4) = o1;
}

// ======================= launch =======================
extern "C" void kernel_launch(void* const* d_in, const int* in_sizes, int n_in,
                              void* d_out, int out_size, void* d_ws, size_t ws_size,
                              hipStream_t stream)
{
    const float* x    = (const float*)d_in[0];
    const float* Wenc = (const float*)d_in[1];
    const float* benc = (const float*)d_in[2];
    const float* Wdec = (const float*)d_in[3];
    const float* bdec = (const float*)d_in[4];
    (void)in_sizes; (void)n_in; (void)out_size; (void)ws_size;
    float* out = (float*)d_out;

    char* ws = (char*)d_ws;
    size_t off = 0;
    float*  cand_val = (float*)(ws + off);  off += (size_t)B_ROWS * CAP * 4;   // 12.6 MB
    int*    cand_idx = (int*)(ws + off);    off += (size_t)B_ROWS * CAP * 4;   // 12.6 MB
    int*    cand_cnt = (int*)(ws + off);    off += (size_t)B_ROWS * 4;
    float*  Tthr     = (float*)(ws + off);  off += (size_t)B_ROWS * 4;
    float*  wsum     = (float*)(ws + off);  off += 256;
    ushort* x_bf16   = (ushort*)(ws + off); off += (size_t)B_ROWS * DIM * 2;   // 8 MB
    int*    run_idx  = (int*)(ws + off);    off += (size_t)B_ROWS * TOPC * 4;
    float*  sel_val  = (float*)(ws + off);  off += (size_t)B_ROWS * KSEL * 4;
    int*    sel_idx  = (int*)(ws + off);    off += (size_t)B_ROWS * KSEL * 4;
    char*   big      = ws + off;            // 128 MB: wenc_bf16, then WdecT

    zero_kernel<<<(B_ROWS + 255) / 256, 256, 0, stream>>>(cand_cnt, wsum);
    wstat_kernel<<<8, 256, 0, stream>>>(Wenc, wsum);
    rownorm_kernel<<<B_ROWS, 256, 0, stream>>>(x, wsum, Tthr);
    conv_bf16_kernel<<<(B_ROWS * DIM) / (256 * 8), 256, 0, stream>>>(x, x_bf16);

    ushort* wenc_bf = (ushort*)big;
    conv_bf16_kernel<<<(int)(((size_t)FDICT * DIM) / (256 * 8)), 256, 0, stream>>>(
        Wenc, wenc_bf);
    enc_gemm_cand<<<dim3(B_ROWS / GM, FDICT / GN), 256, 0, stream>>>(
        x_bf16, wenc_bf, benc, Tthr, cand_val, cand_idx, cand_cnt);

    select_kernel<<<B_ROWS, 256, 0, stream>>>(cand_val, cand_idx, cand_cnt, run_idx);
    refine_np_kernel<<<B_ROWS / 2, 256, 0, stream>>>(x, Wenc, benc, run_idx, sel_val, sel_idx);

    ushort* WdecT = (ushort*)big;   // reuse: encode phase done
    transpose_wdec_bf16<<<dim3(FDICT / 64, DIM / 64), 256, 0, stream>>>(Wdec, WdecT);
    decode_full_kernel<<<B_ROWS, 256, 0, stream>>>(WdecT, sel_val, sel_idx, bdec, out);
}

// Round 9
// 985.961 us; speedup vs baseline: 4.9992x; 1.1262x over previous
//
#include <hip/hip_runtime.h>
#include <stdint.h>

#define B_ROWS 2048
#define DIM    2048
#define FDICT  32768
#define KSEL   64
#define TOPC   96       // candidate list; refined bit-exactly vs np.einsum fp32
#define CAP    1536     // per-row candidate capacity (mean ~616 @ 2.35 sigma)
#define THRFAC 2.35f
#define WSAMPN (64 * DIM)   // Wenc sample count for sigma_w estimate

typedef __attribute__((ext_vector_type(8))) short bf16x8;
typedef __attribute__((ext_vector_type(4))) float f32x4;

__device__ __forceinline__ float bf16_to_f32(ushort u)
{
    return __uint_as_float(((uint32_t)u) << 16);
}

// ======================= init: zero counters =======================
__global__ __launch_bounds__(256) void zero_kernel(int* __restrict__ cand_cnt,
                                                   float* __restrict__ wsum)
{
    int i = blockIdx.x * 256 + threadIdx.x;
    if (i < B_ROWS) cand_cnt[i] = 0;
    if (i == 0) wsum[0] = 0.f;
}

// ======================= sigma_w estimate (sample 64 Wenc rows) ==============
__global__ __launch_bounds__(256) void wstat_kernel(
    const float* __restrict__ Wenc, float* __restrict__ wsum)
{
    __shared__ float red[256];
    const int tid = threadIdx.x;
    float s = 0.f;
    for (int i = blockIdx.x * 256 + tid; i < WSAMPN / 4; i += 8 * 256) {
        float4 w = ((const float4*)Wenc)[i];
        s += w.x * w.x + w.y * w.y + w.z * w.z + w.w * w.w;
    }
    red[tid] = s;
    __syncthreads();
    for (int o = 128; o > 0; o >>= 1) {
        if (tid < o) red[tid] += red[tid + o];
        __syncthreads();
    }
    if (tid == 0) atomicAdd(wsum, red[0]);
}

// ======================= per-row threshold: T = f * sigma_w * ||x_row|| ======
__global__ __launch_bounds__(256) void rownorm_kernel(
    const float* __restrict__ x, const float* __restrict__ wsum,
    float* __restrict__ T)
{
    __shared__ float red[256];
    const int row = blockIdx.x;
    const int tid = threadIdx.x;
    const float4* xr = (const float4*)(x + (size_t)row * DIM);
    float s = 0.f;
#pragma unroll
    for (int u = 0; u < 2; ++u) {
        float4 v = xr[tid + u * 256];
        s += v.x * v.x + v.y * v.y + v.z * v.z + v.w * v.w;
    }
    red[tid] = s;
    __syncthreads();
    for (int o = 128; o > 0; o >>= 1) {
        if (tid < o) red[tid] += red[tid + o];
        __syncthreads();
    }
    if (tid == 0)
        T[row] = THRFAC * sqrtf(wsum[0] / (float)WSAMPN) * sqrtf(red[0]);
}

// -------- fp32 -> bf16 (RNE) streaming convert --------
__global__ __launch_bounds__(256) void conv_bf16_kernel(
    const float* __restrict__ src, ushort* __restrict__ dst)
{
    const size_t i = ((size_t)blockIdx.x * 256 + threadIdx.x) * 8;
    float4 u = *(const float4*)(src + i);
    float4 v = *(const float4*)(src + i + 4);
    union { ushort s[8]; bf16x8 w; } o;
    float t[8] = {u.x, u.y, u.z, u.w, v.x, v.y, v.z, v.w};
#pragma unroll
    for (int j = 0; j < 8; ++j) {
        union { __bf16 h; ushort s; } cv;
        cv.h = (__bf16)t[j];
        o.s[j] = cv.s;
    }
    *(bf16x8*)(dst + i) = o.w;
}

// ====== encode GEMM: bf16 MFMA, T2 swizzle + T3 2-phase dbuf + T4 counted
// vmcnt + T1 XCD-chunked block swizzle. Candidate emit by threshold.
#define GM 128
#define GN 128
#define GK 64
#define NT (DIM / GK)   // 32 K-tiles

__device__ __forceinline__ void gload_lds16(const void* g, void* l)
{
    __builtin_amdgcn_global_load_lds(
        (const __attribute__((address_space(1))) void*)(uintptr_t)g,
        (__attribute__((address_space(3))) void*)(uint32_t)(uintptr_t)l,
        16, 0, 0);
}

__global__ __launch_bounds__(256) void enc_gemm_cand(
    const ushort* __restrict__ A,    // x_bf16    [B_ROWS][DIM]
    const ushort* __restrict__ Bw,   // Wenc_bf16 [FDICT][DIM]
    const float* __restrict__ benc,
    const float* __restrict__ T,     // [B_ROWS] per-row threshold
    float* __restrict__ cand_val,    // [B_ROWS][CAP]
    int* __restrict__ cand_idx,      // [B_ROWS][CAP]
    int* __restrict__ cand_cnt)      // [B_ROWS]
{
    __shared__ __align__(16) ushort As[2][GM * GK];   // 32 KB
    __shared__ __align__(16) ushort Bs[2][GN * GK];   // 32 KB

    const int tid  = threadIdx.x;
    const int lane = tid & 63;
    const int wv   = tid >> 6;
    const int wr   = wv >> 1, wc = wv & 1;
    const int lr   = lane & 15, lg = lane >> 4;

    // T1: bijective XCD-chunked swizzle. 4096 blocks, 8 XCDs -> 512 each.
    // Row-block fast within a chunk: each XCD owns 32 whole W-panels.
    const int bid = blockIdx.x;
    const int nf  = (bid & 7) * 512 + (bid >> 3);
    const int row0 = (nf & 15) * GM;
    const int col0 = (nf >> 4) * GN;

    const ushort* aSrc = A  + (size_t)row0 * DIM;
    const ushort* bSrc = Bw + (size_t)col0 * DIM;

    const int srow   = (lane >> 3);                    // row within 8-row group
    const int scolsw = ((lane & 7) ^ srow) * 8;        // pre-swizzled source col

    f32x4 acc[4][4] = {};

    // per-wave staging of one K-tile: 4 x (gloadA + gloadB) = 8 vmem ops/wave
#define STAGE(bsel, kt)                                                        \
    {                                                                          \
        const int k0_ = (kt) * GK;                                             \
        _Pragma("unroll")                                                      \
        for (int i_ = 0; i_ < 4; ++i_) {                                       \
            const int g_ = wv * 4 + i_;                                        \
            const int r_ = g_ * 8 + srow;                                      \
            gload_lds16(aSrc + (size_t)r_ * DIM + k0_ + scolsw,                \
                        (char*)&As[bsel][0] + g_ * 1024);                      \
            gload_lds16(bSrc + (size_t)r_ * DIM + k0_ + scolsw,                \
                        (char*)&Bs[bsel][0] + g_ * 1024);                      \
        }                                                                      \
    }

    STAGE(0, 0);
    int cur = 0;
    for (int kt = 0; kt < NT; ++kt) {
        // all waves finished ds_reads of buf cur^1 (previous iter) -> safe to
        // overwrite it with tile kt+1
        __builtin_amdgcn_s_barrier();
        if (kt + 1 < NT) {
            STAGE(cur ^ 1, kt + 1);
            // wait ONLY tile kt's 8 loads (oldest); kt+1's 8 stay in flight
            asm volatile("s_waitcnt vmcnt(8)" ::: "memory");
        } else {
            asm volatile("s_waitcnt vmcnt(0)" ::: "memory");
        }
        __builtin_amdgcn_s_barrier();        // tile kt resident for all waves
        __builtin_amdgcn_sched_barrier(0);

        bf16x8 af[2][4], bfr[2][4];
#pragma unroll
        for (int kk = 0; kk < 2; ++kk) {
            const int csw = (kk * 32 + lg * 8) ^ ((lr & 7) << 3);
#pragma unroll
            for (int mi = 0; mi < 4; ++mi)
                af[kk][mi] = *(const bf16x8*)(&As[cur][0] + (wr * 64 + mi * 16 + lr) * GK + csw);
#pragma unroll
            for (int ni = 0; ni < 4; ++ni)
                bfr[kk][ni] = *(const bf16x8*)(&Bs[cur][0] + (wc * 64 + ni * 16 + lr) * GK + csw);
        }
#pragma unroll
        for (int kk = 0; kk < 2; ++kk)
#pragma unroll
            for (int mi = 0; mi < 4; ++mi)
#pragma unroll
                for (int ni = 0; ni < 4; ++ni)
                    acc[mi][ni] = __builtin_amdgcn_mfma_f32_16x16x32_bf16(
                        af[kk][mi], bfr[kk][ni], acc[mi][ni], 0, 0, 0);
        cur ^= 1;
    }

    float bias[4];
#pragma unroll
    for (int ni = 0; ni < 4; ++ni)
        bias[ni] = benc[col0 + wc * 64 + ni * 16 + lr];

    // C/D layout (verified r4): col = lane&15, row = (lane>>4)*4 + reg
#pragma unroll
    for (int mi = 0; mi < 4; ++mi) {
#pragma unroll
        for (int r = 0; r < 4; ++r) {
            const int rloc = wr * 64 + mi * 16 + lg * 4 + r;
            const float t = T[row0 + rloc];
#pragma unroll
            for (int ni = 0; ni < 4; ++ni) {
                const float v = acc[mi][ni][r] + bias[ni];
                if (fabsf(v) >= t) {
                    const int grow = row0 + rloc;
                    const int gcol = col0 + wc * 64 + ni * 16 + lr;
                    int pos = atomicAdd(&cand_cnt[grow], 1);
                    if (pos < CAP) {
                        cand_val[(size_t)grow * CAP + pos] = v;
                        cand_idx[(size_t)grow * CAP + pos] = gcol;
                    }
                }
            }
        }
    }
#undef STAGE
}

// ============ exact radix select: candidates -> top-TOPC indices =============
__global__ __launch_bounds__(256) void select_kernel(
    const float* __restrict__ cand_val,
    const int* __restrict__ cand_idx,
    const int* __restrict__ cand_cnt,
    int* __restrict__ run_idx)
{
    const int row = blockIdx.x;
    const int tid = threadIdx.x;

    __shared__ uint32_t ua[CAP];
    __shared__ int      si[CAP];
    __shared__ int      hist[256];
    __shared__ uint32_t sh_prefix;
    __shared__ int      sh_cgt, c_out, c_eq;

    int cnt = cand_cnt[row];
    if (cnt > CAP) cnt = CAP;

    for (int j = tid; j < cnt; j += 256) {
        ua[j] = __float_as_uint(cand_val[(size_t)row * CAP + j]) & 0x7fffffffu;
        si[j] = cand_idx[(size_t)row * CAP + j];
    }
    if (tid == 0) { sh_prefix = 0u; sh_cgt = 0; c_out = 0; c_eq = 0; }
    __syncthreads();

    if (cnt <= TOPC) {
        if (tid < TOPC) run_idx[(size_t)row * TOPC + tid] = (tid < cnt) ? si[tid] : -1;
        return;
    }

    for (int p = 3; p >= 0; --p) {
        hist[tid] = 0;
        __syncthreads();
        const uint32_t mask = (p == 3) ? 0u : (0xffffffffu << ((p + 1) * 8));
        const uint32_t pref = sh_prefix;
        for (int j = tid; j < cnt; j += 256) {
            uint32_t u = ua[j];
            if ((u & mask) == pref)
                atomicAdd(&hist[(u >> (p * 8)) & 255], 1);
        }
        __syncthreads();
        if (tid == 0) {
            int cum = sh_cgt;
            int chosen = 0;
            for (int b = 255; b >= 0; --b) {
                int c = hist[b];
                if (cum + c >= TOPC) { chosen = b; break; }
                cum += c;
            }
            sh_prefix = sh_prefix | ((uint32_t)chosen << (p * 8));
            sh_cgt = cum;
        }
        __syncthreads();
    }

    const uint32_t uth = sh_prefix;
    for (int j = tid; j < cnt; j += 256) {
        if (ua[j] > uth) {
            int pos = atomicAdd(&c_out, 1);
            run_idx[(size_t)row * TOPC + pos] = si[j];
        }
    }
    __syncthreads();
    const int base = c_out;
    for (int j = tid; j < cnt; j += 256) {
        if (ua[j] == uth) {
            int e = atomicAdd(&c_eq, 1);
            int slot = base + e;
            if (slot < TOPC) run_idx[(size_t)row * TOPC + slot] = si[j];
        }
    }
}

// ============ np.einsum-bit-exact refinement of TOPC candidates ==============
// numpy fp32 SSE chain: 4 accumulators over d%4 ascending, round(mul) then
// round(add) (no FMA), combined (a0+a2)+(a1+a3), then + b_enc.
// Ping-pong double-buffered loads (2x8 float4 in flight) for MLP.
__global__ __launch_bounds__(256) void refine_np_kernel(
    const float* __restrict__ x,
    const float* __restrict__ Wenc,
    const float* __restrict__ benc,
    const int* __restrict__ run_idx,
    float* __restrict__ sel_val,
    int* __restrict__ sel_idx)
{
    const int half = threadIdx.x >> 7;      // row within block (0..1)
    const int cid  = threadIdx.x & 127;     // candidate id (<TOPC active)
    const int row  = blockIdx.x * 2 + half;

    __shared__ __align__(16) float xs[2][DIM];
    __shared__ float cval[2][TOPC];
    __shared__ int   cidx[2][TOPC];

    {
        const float4* src = (const float4*)(x + (size_t)blockIdx.x * 2 * DIM);
        for (int i = threadIdx.x; i < 2 * DIM / 4; i += 256)
            ((float4*)xs)[i] = src[i];
    }
    if (cid < TOPC) cidx[half][cid] = run_idx[(size_t)row * TOPC + cid];
    __syncthreads();

    if (cid < TOPC) {
        const int f = cidx[half][cid];
        if (f >= 0) {
            const float4* w4 = (const float4*)(Wenc + (size_t)f * DIM);
            const float4* x4 = (const float4*)xs[half];
            float a0 = 0.f, a1 = 0.f, a2 = 0.f, a3 = 0.f;
            float4 pa[8], pb[8];
#pragma unroll
            for (int u = 0; u < 8; ++u) pa[u] = w4[u];
            for (int t0 = 0; t0 < DIM / 4; t0 += 16) {
#pragma unroll
                for (int u = 0; u < 8; ++u) pb[u] = w4[t0 + 8 + u];
#pragma unroll
                for (int u = 0; u < 8; ++u) {
                    float4 xv = x4[t0 + u];
                    a0 = __fadd_rn(a0, __fmul_rn(xv.x, pa[u].x));
                    a1 = __fadd_rn(a1, __fmul_rn(xv.y, pa[u].y));
                    a2 = __fadd_rn(a2, __fmul_rn(xv.z, pa[u].z));
                    a3 = __fadd_rn(a3, __fmul_rn(xv.w, pa[u].w));
                }
                if (t0 + 16 < DIM / 4) {
#pragma unroll
                    for (int u = 0; u < 8; ++u) pa[u] = w4[t0 + 16 + u];
                }
#pragma unroll
                for (int u = 0; u < 8; ++u) {
                    float4 xv = x4[t0 + 8 + u];
                    a0 = __fadd_rn(a0, __fmul_rn(xv.x, pb[u].x));
                    a1 = __fadd_rn(a1, __fmul_rn(xv.y, pb[u].y));
                    a2 = __fadd_rn(a2, __fmul_rn(xv.z, pb[u].z));
                    a3 = __fadd_rn(a3, __fmul_rn(xv.w, pb[u].w));
                }
            }
            float v = __fadd_rn(__fadd_rn(a0, a2), __fadd_rn(a1, a3));
            cval[half][cid] = __fadd_rn(v, benc[f]);
        } else {
            cval[half][cid] = 0.f;
        }
    }
    __syncthreads();

    if (cid < TOPC) {
        const int f = cidx[half][cid];
        if (f >= 0) {
            const uint32_t av = __float_as_uint(cval[half][cid]) & 0x7fffffffu;
            int rank = 0;
            for (int u = 0; u < TOPC; ++u) {
                if (u == cid) continue;
                int fu = cidx[half][u];
                if (fu < 0) continue;
                uint32_t au = __float_as_uint(cval[half][u]) & 0x7fffffffu;
                if (au > av || (au == av && fu < f)) ++rank;
            }
            if (rank < KSEL) {
                sel_val[(size_t)row * KSEL + rank] = cval[half][cid];
                sel_idx[(size_t)row * KSEL + rank] = f;
            }
        }
    }
}

// ================= decode: Wdec -> bf16 [F][D], one-pass gather ==============
__global__ __launch_bounds__(256) void transpose_wdec_bf16(
    const float* __restrict__ Wdec,   // [DIM][FDICT]
    ushort* __restrict__ WdecT)       // [FDICT][DIM] bf16
{
    __shared__ float t[64][65];
    const int f0 = blockIdx.x * 64;
    const int d0 = blockIdx.y * 64;
    const int tx = threadIdx.x & 63;
    const int ty = threadIdx.x >> 6;  // 0..3
#pragma unroll
    for (int r = 0; r < 16; ++r)
        t[ty * 16 + r][tx] = Wdec[(size_t)(d0 + ty * 16 + r) * FDICT + f0 + tx];
    __syncthreads();
#pragma unroll
    for (int r = 0; r < 16; ++r) {
        union { __bf16 h; ushort s; } cv;
        cv.h = (__bf16)t[tx][ty * 16 + r];
        WdecT[(size_t)(f0 + ty * 16 + r) * DIM + d0 + tx] = cv.s;
    }
}

__global__ __launch_bounds__(256) void decode_full_kernel(
    const ushort* __restrict__ WdecT,   // [FDICT][DIM] bf16
    const float* __restrict__ sel_val,
    const int* __restrict__ sel_idx,
    const float* __restrict__ bdec,
    float* __restrict__ out)
{
    const int row = blockIdx.x;
    const int tid = threadIdx.x;
    __shared__ float vv[KSEL];
    __shared__ int   ff[KSEL];
    if (tid < KSEL) {
        vv[tid] = sel_val[row * KSEL + tid];
        ff[tid] = sel_idx[row * KSEL + tid];
    }
    __syncthreads();
    const int d0 = tid * 8;
    float acc[8];
    {
        float4 b0 = *(const float4*)(bdec + d0);
        float4 b1 = *(const float4*)(bdec + d0 + 4);
        acc[0] = b0.x; acc[1] = b0.y; acc[2] = b0.z; acc[3] = b0.w;
        acc[4] = b1.x; acc[5] = b1.y; acc[6] = b1.z; acc[7] = b1.w;
    }
    for (int k = 0; k < KSEL; ++k) {
        const float v = vv[k];
        union { ushort s[8]; bf16x8 w; } u;
        u.w = *(const bf16x8*)(WdecT + (size_t)ff[k] * DIM + d0);
#pragma unroll
        for (int j = 0; j < 8; ++j)
            acc[j] = fmaf(v, bf16_to_f32(u.s[j]), acc[j]);
    }
    float* orow = out + (size_t)row * DIM + d0;
    float4 o0 = {acc[0], acc[1], acc[2], acc[3]};
    float4 o1 = {acc[4], acc[5], acc[6], acc[7]};
    *(float4*)(orow + 0) = o0;
    *(float4*)(orow + 4) = o1;
}

// ======================= launch =======================
extern "C" void kernel_launch(void* const* d_in, const int* in_sizes, int n_in,
                              void* d_out, int out_size, void* d_ws, size_t ws_size,
                              hipStream_t stream)
{
    const float* x    = (const float*)d_in[0];
    const float* Wenc = (const float*)d_in[1];
    const float* benc = (const float*)d_in[2];
    const float* Wdec = (const float*)d_in[3];
    const float* bdec = (const float*)d_in[4];
    (void)in_sizes; (void)n_in; (void)out_size; (void)ws_size;
    float* out = (float*)d_out;

    char* ws = (char*)d_ws;
    size_t off = 0;
    float*  cand_val = (float*)(ws + off);  off += (size_t)B_ROWS * CAP * 4;   // 12.6 MB
    int*    cand_idx = (int*)(ws + off);    off += (size_t)B_ROWS * CAP * 4;   // 12.6 MB
    int*    cand_cnt = (int*)(ws + off);    off += (size_t)B_ROWS * 4;
    float*  Tthr     = (float*)(ws + off);  off += (size_t)B_ROWS * 4;
    float*  wsum     = (float*)(ws + off);  off += 256;
    ushort* x_bf16   = (ushort*)(ws + off); off += (size_t)B_ROWS * DIM * 2;   // 8 MB
    int*    run_idx  = (int*)(ws + off);    off += (size_t)B_ROWS * TOPC * 4;
    float*  sel_val  = (float*)(ws + off);  off += (size_t)B_ROWS * KSEL * 4;
    int*    sel_idx  = (int*)(ws + off);    off += (size_t)B_ROWS * KSEL * 4;
    char*   big      = ws + off;            // 128 MB: wenc_bf16, then WdecT

    zero_kernel<<<(B_ROWS + 255) / 256, 256, 0, stream>>>(cand_cnt, wsum);
    wstat_kernel<<<8, 256, 0, stream>>>(Wenc, wsum);
    rownorm_kernel<<<B_ROWS, 256, 0, stream>>>(x, wsum, Tthr);
    conv_bf16_kernel<<<(B_ROWS * DIM) / (256 * 8), 256, 0, stream>>>(x, x_bf16);

    ushort* wenc_bf = (ushort*)big;
    conv_bf16_kernel<<<(int)(((size_t)FDICT * DIM) / (256 * 8)), 256, 0, stream>>>(
        Wenc, wenc_bf);
    enc_gemm_cand<<<(B_ROWS / GM) * (FDICT / GN), 256, 0, stream>>>(
        x_bf16, wenc_bf, benc, Tthr, cand_val, cand_idx, cand_cnt);

    select_kernel<<<B_ROWS, 256, 0, stream>>>(cand_val, cand_idx, cand_cnt, run_idx);
    refine_np_kernel<<<B_ROWS / 2, 256, 0, stream>>>(x, Wenc, benc, run_idx, sel_val, sel_idx);

    ushort* WdecT = (ushort*)big;   // reuse: encode phase done
    transpose_wdec_bf16<<<dim3(FDICT / 64, DIM / 64), 256, 0, stream>>>(Wdec, WdecT);
    decode_full_kernel<<<B_ROWS, 256, 0, stream>>>(WdecT, sel_val, sel_idx, bdec, out);
}

// Round 10
// 980.619 us; speedup vs baseline: 5.0265x; 1.0054x over previous
//
#include <hip/hip_runtime.h>
#include <stdint.h>

#define B_ROWS 2048
#define DIM    2048
#define FDICT  32768
#define KSEL   64
#define TOPC   96       // candidate list; refined bit-exactly vs np.einsum fp32
#define CAP    1536     // per-row candidate capacity (mean ~616 @ 2.35 sigma)
#define THRFAC 2.35f
#define WSAMPN (64 * DIM)   // Wenc sample count for sigma_w estimate

typedef __attribute__((ext_vector_type(8))) short bf16x8;
typedef __attribute__((ext_vector_type(4))) float f32x4;

__device__ __forceinline__ float bf16_to_f32(ushort u)
{
    return __uint_as_float(((uint32_t)u) << 16);
}

// ======================= init: zero counters =======================
__global__ __launch_bounds__(256) void zero_kernel(int* __restrict__ cand_cnt,
                                                   float* __restrict__ wsum)
{
    int i = blockIdx.x * 256 + threadIdx.x;
    if (i < B_ROWS) cand_cnt[i] = 0;
    if (i == 0) wsum[0] = 0.f;
}

// ======================= sigma_w estimate (sample 64 Wenc rows) ==============
__global__ __launch_bounds__(256) void wstat_kernel(
    const float* __restrict__ Wenc, float* __restrict__ wsum)
{
    __shared__ float red[256];
    const int tid = threadIdx.x;
    float s = 0.f;
    for (int i = blockIdx.x * 256 + tid; i < WSAMPN / 4; i += 8 * 256) {
        float4 w = ((const float4*)Wenc)[i];
        s += w.x * w.x + w.y * w.y + w.z * w.z + w.w * w.w;
    }
    red[tid] = s;
    __syncthreads();
    for (int o = 128; o > 0; o >>= 1) {
        if (tid < o) red[tid] += red[tid + o];
        __syncthreads();
    }
    if (tid == 0) atomicAdd(wsum, red[0]);
}

// ======================= per-row threshold: T = f * sigma_w * ||x_row|| ======
__global__ __launch_bounds__(256) void rownorm_kernel(
    const float* __restrict__ x, const float* __restrict__ wsum,
    float* __restrict__ T)
{
    __shared__ float red[256];
    const int row = blockIdx.x;
    const int tid = threadIdx.x;
    const float4* xr = (const float4*)(x + (size_t)row * DIM);
    float s = 0.f;
#pragma unroll
    for (int u = 0; u < 2; ++u) {
        float4 v = xr[tid + u * 256];
        s += v.x * v.x + v.y * v.y + v.z * v.z + v.w * v.w;
    }
    red[tid] = s;
    __syncthreads();
    for (int o = 128; o > 0; o >>= 1) {
        if (tid < o) red[tid] += red[tid + o];
        __syncthreads();
    }
    if (tid == 0)
        T[row] = THRFAC * sqrtf(wsum[0] / (float)WSAMPN) * sqrtf(red[0]);
}

// -------- fp32 -> bf16 (RNE) streaming convert --------
__global__ __launch_bounds__(256) void conv_bf16_kernel(
    const float* __restrict__ src, ushort* __restrict__ dst)
{
    const size_t i = ((size_t)blockIdx.x * 256 + threadIdx.x) * 8;
    float4 u = *(const float4*)(src + i);
    float4 v = *(const float4*)(src + i + 4);
    union { ushort s[8]; bf16x8 w; } o;
    float t[8] = {u.x, u.y, u.z, u.w, v.x, v.y, v.z, v.w};
#pragma unroll
    for (int j = 0; j < 8; ++j) {
        union { __bf16 h; ushort s; } cv;
        cv.h = (__bf16)t[j];
        o.s[j] = cv.s;
    }
    *(bf16x8*)(dst + i) = o.w;
}

// ====== encode GEMM: bf16 MFMA, GK=32 (32KB LDS -> 5 blocks/CU TLP),
// T2 swizzle + T3 2-phase dbuf + T4 counted vmcnt + T1 XCD swizzle.
#define GM 128
#define GN 128
#define GK 32
#define NT (DIM / GK)   // 64 K-tiles

__device__ __forceinline__ void gload_lds16(const void* g, void* l)
{
    __builtin_amdgcn_global_load_lds(
        (const __attribute__((address_space(1))) void*)(uintptr_t)g,
        (__attribute__((address_space(3))) void*)(uint32_t)(uintptr_t)l,
        16, 0, 0);
}

__global__ __launch_bounds__(256) void enc_gemm_cand(
    const ushort* __restrict__ A,    // x_bf16    [B_ROWS][DIM]
    const ushort* __restrict__ Bw,   // Wenc_bf16 [FDICT][DIM]
    const float* __restrict__ benc,
    const float* __restrict__ T,     // [B_ROWS] per-row threshold
    float* __restrict__ cand_val,    // [B_ROWS][CAP]
    int* __restrict__ cand_idx,      // [B_ROWS][CAP]
    int* __restrict__ cand_cnt)      // [B_ROWS]
{
    __shared__ __align__(16) ushort As[2][GM * GK];   // 2 x 8 KB
    __shared__ __align__(16) ushort Bs[2][GN * GK];   // 2 x 8 KB

    const int tid  = threadIdx.x;
    const int lane = tid & 63;
    const int wv   = tid >> 6;
    const int wr   = wv >> 1, wc = wv & 1;
    const int lr   = lane & 15, lg = lane >> 4;

    // T1: bijective XCD-chunked swizzle. 4096 blocks, 8 XCDs -> 512 each.
    const int bid = blockIdx.x;
    const int nf  = (bid & 7) * 512 + (bid >> 3);
    const int row0 = (nf & 15) * GM;
    const int col0 = (nf >> 4) * GN;

    const ushort* aSrc = A  + (size_t)row0 * DIM;
    const ushort* bSrc = Bw + (size_t)col0 * DIM;

    f32x4 acc[4][4] = {};

    // Staging one K-tile (A 8KB + B 8KB): per wave 2 A ops + 2 B ops.
    // LDS is written linearly (wave-uniform base, lane x 16B implicit);
    // source column block pre-swizzled: LDS[r][b] = global[r][b ^ ((r>>1)&3)].
#define STAGE(bsel, kt)                                                        \
    {                                                                          \
        const int k0_ = (kt) * GK;                                             \
        _Pragma("unroll")                                                      \
        for (int i_ = 0; i_ < 2; ++i_) {                                       \
            const int q0_ = wv * 128 + i_ * 64;                                \
            const int q_  = q0_ + lane;                                        \
            const int r_  = q_ >> 2;                                           \
            const int sb_ = (q_ & 3) ^ ((r_ >> 1) & 3);                        \
            gload_lds16(aSrc + (size_t)r_ * DIM + k0_ + sb_ * 8,               \
                        (char*)&As[bsel][0] + q0_ * 16);                       \
            gload_lds16(bSrc + (size_t)r_ * DIM + k0_ + sb_ * 8,               \
                        (char*)&Bs[bsel][0] + q0_ * 16);                       \
        }                                                                      \
    }

    STAGE(0, 0);
    int cur = 0;
    for (int kt = 0; kt < NT; ++kt) {
        // all waves finished ds_reads of buf cur^1 (previous iter) -> safe to
        // overwrite it with tile kt+1
        __builtin_amdgcn_s_barrier();
        if (kt + 1 < NT) {
            STAGE(cur ^ 1, kt + 1);
            // wait ONLY tile kt's 4 loads (oldest); kt+1's 4 stay in flight
            asm volatile("s_waitcnt vmcnt(4)" ::: "memory");
        } else {
            asm volatile("s_waitcnt vmcnt(0)" ::: "memory");
        }
        __builtin_amdgcn_s_barrier();        // tile kt resident for all waves
        __builtin_amdgcn_sched_barrier(0);

        bf16x8 af[4], bfr[4];
#pragma unroll
        for (int mi = 0; mi < 4; ++mi) {
            const int R = wr * 64 + mi * 16 + lr;
            af[mi] = *(const bf16x8*)(&As[cur][0] + R * GK + ((lg ^ ((R >> 1) & 3)) * 8));
        }
#pragma unroll
        for (int ni = 0; ni < 4; ++ni) {
            const int R = wc * 64 + ni * 16 + lr;
            bfr[ni] = *(const bf16x8*)(&Bs[cur][0] + R * GK + ((lg ^ ((R >> 1) & 3)) * 8));
        }
#pragma unroll
        for (int mi = 0; mi < 4; ++mi)
#pragma unroll
            for (int ni = 0; ni < 4; ++ni)
                acc[mi][ni] = __builtin_amdgcn_mfma_f32_16x16x32_bf16(
                    af[mi], bfr[ni], acc[mi][ni], 0, 0, 0);
        cur ^= 1;
    }

    float bias[4];
#pragma unroll
    for (int ni = 0; ni < 4; ++ni)
        bias[ni] = benc[col0 + wc * 64 + ni * 16 + lr];

    // C/D layout (verified r4): col = lane&15, row = (lane>>4)*4 + reg
#pragma unroll
    for (int mi = 0; mi < 4; ++mi) {
#pragma unroll
        for (int r = 0; r < 4; ++r) {
            const int rloc = wr * 64 + mi * 16 + lg * 4 + r;
            const float t = T[row0 + rloc];
#pragma unroll
            for (int ni = 0; ni < 4; ++ni) {
                const float v = acc[mi][ni][r] + bias[ni];
                if (fabsf(v) >= t) {
                    const int grow = row0 + rloc;
                    const int gcol = col0 + wc * 64 + ni * 16 + lr;
                    int pos = atomicAdd(&cand_cnt[grow], 1);
                    if (pos < CAP) {
                        cand_val[(size_t)grow * CAP + pos] = v;
                        cand_idx[(size_t)grow * CAP + pos] = gcol;
                    }
                }
            }
        }
    }
#undef STAGE
}

// ============ exact radix select: candidates -> top-TOPC indices =============
__global__ __launch_bounds__(256) void select_kernel(
    const float* __restrict__ cand_val,
    const int* __restrict__ cand_idx,
    const int* __restrict__ cand_cnt,
    int* __restrict__ run_idx)
{
    const int row = blockIdx.x;
    const int tid = threadIdx.x;

    __shared__ uint32_t ua[CAP];
    __shared__ int      si[CAP];
    __shared__ int      hist[256];
    __shared__ uint32_t sh_prefix;
    __shared__ int      sh_cgt, c_out, c_eq;

    int cnt = cand_cnt[row];
    if (cnt > CAP) cnt = CAP;

    for (int j = tid; j < cnt; j += 256) {
        ua[j] = __float_as_uint(cand_val[(size_t)row * CAP + j]) & 0x7fffffffu;
        si[j] = cand_idx[(size_t)row * CAP + j];
    }
    if (tid == 0) { sh_prefix = 0u; sh_cgt = 0; c_out = 0; c_eq = 0; }
    __syncthreads();

    if (cnt <= TOPC) {
        if (tid < TOPC) run_idx[(size_t)row * TOPC + tid] = (tid < cnt) ? si[tid] : -1;
        return;
    }

    for (int p = 3; p >= 0; --p) {
        hist[tid] = 0;
        __syncthreads();
        const uint32_t mask = (p == 3) ? 0u : (0xffffffffu << ((p + 1) * 8));
        const uint32_t pref = sh_prefix;
        for (int j = tid; j < cnt; j += 256) {
            uint32_t u = ua[j];
            if ((u & mask) == pref)
                atomicAdd(&hist[(u >> (p * 8)) & 255], 1);
        }
        __syncthreads();
        if (tid == 0) {
            int cum = sh_cgt;
            int chosen = 0;
            for (int b = 255; b >= 0; --b) {
                int c = hist[b];
                if (cum + c >= TOPC) { chosen = b; break; }
                cum += c;
            }
            sh_prefix = sh_prefix | ((uint32_t)chosen << (p * 8));
            sh_cgt = cum;
        }
        __syncthreads();
    }

    const uint32_t uth = sh_prefix;
    for (int j = tid; j < cnt; j += 256) {
        if (ua[j] > uth) {
            int pos = atomicAdd(&c_out, 1);
            run_idx[(size_t)row * TOPC + pos] = si[j];
        }
    }
    __syncthreads();
    const int base = c_out;
    for (int j = tid; j < cnt; j += 256) {
        if (ua[j] == uth) {
            int e = atomicAdd(&c_eq, 1);
            int slot = base + e;
            if (slot < TOPC) run_idx[(size_t)row * TOPC + slot] = si[j];
        }
    }
}

// ============ np.einsum-bit-exact refinement of TOPC candidates ==============
// numpy fp32 SSE chain: 4 accumulators over d%4 ascending, round(mul) then
// round(add) (no FMA), combined (a0+a2)+(a1+a3), then + b_enc.
// Ping-pong double-buffered loads (2x8 float4 in flight) for MLP.
__global__ __launch_bounds__(256) void refine_np_kernel(
    const float* __restrict__ x,
    const float* __restrict__ Wenc,
    const float* __restrict__ benc,
    const int* __restrict__ run_idx,
    float* __restrict__ sel_val,
    int* __restrict__ sel_idx)
{
    const int half = threadIdx.x >> 7;      // row within block (0..1)
    const int cid  = threadIdx.x & 127;     // candidate id (<TOPC active)
    const int row  = blockIdx.x * 2 + half;

    __shared__ __align__(16) float xs[2][DIM];
    __shared__ float cval[2][TOPC];
    __shared__ int   cidx[2][TOPC];

    {
        const float4* src = (const float4*)(x + (size_t)blockIdx.x * 2 * DIM);
        for (int i = threadIdx.x; i < 2 * DIM / 4; i += 256)
            ((float4*)xs)[i] = src[i];
    }
    if (cid < TOPC) cidx[half][cid] = run_idx[(size_t)row * TOPC + cid];
    __syncthreads();

    if (cid < TOPC) {
        const int f = cidx[half][cid];
        if (f >= 0) {
            const float4* w4 = (const float4*)(Wenc + (size_t)f * DIM);
            const float4* x4 = (const float4*)xs[half];
            float a0 = 0.f, a1 = 0.f, a2 = 0.f, a3 = 0.f;
            float4 pa[8], pb[8];
#pragma unroll
            for (int u = 0; u < 8; ++u) pa[u] = w4[u];
            for (int t0 = 0; t0 < DIM / 4; t0 += 16) {
#pragma unroll
                for (int u = 0; u < 8; ++u) pb[u] = w4[t0 + 8 + u];
#pragma unroll
                for (int u = 0; u < 8; ++u) {
                    float4 xv = x4[t0 + u];
                    a0 = __fadd_rn(a0, __fmul_rn(xv.x, pa[u].x));
                    a1 = __fadd_rn(a1, __fmul_rn(xv.y, pa[u].y));
                    a2 = __fadd_rn(a2, __fmul_rn(xv.z, pa[u].z));
                    a3 = __fadd_rn(a3, __fmul_rn(xv.w, pa[u].w));
                }
                if (t0 + 16 < DIM / 4) {
#pragma unroll
                    for (int u = 0; u < 8; ++u) pa[u] = w4[t0 + 16 + u];
                }
#pragma unroll
                for (int u = 0; u < 8; ++u) {
                    float4 xv = x4[t0 + 8 + u];
                    a0 = __fadd_rn(a0, __fmul_rn(xv.x, pb[u].x));
                    a1 = __fadd_rn(a1, __fmul_rn(xv.y, pb[u].y));
                    a2 = __fadd_rn(a2, __fmul_rn(xv.z, pb[u].z));
                    a3 = __fadd_rn(a3, __fmul_rn(xv.w, pb[u].w));
                }
            }
            float v = __fadd_rn(__fadd_rn(a0, a2), __fadd_rn(a1, a3));
            cval[half][cid] = __fadd_rn(v, benc[f]);
        } else {
            cval[half][cid] = 0.f;
        }
    }
    __syncthreads();

    if (cid < TOPC) {
        const int f = cidx[half][cid];
        if (f >= 0) {
            const uint32_t av = __float_as_uint(cval[half][cid]) & 0x7fffffffu;
            int rank = 0;
            for (int u = 0; u < TOPC; ++u) {
                if (u == cid) continue;
                int fu = cidx[half][u];
                if (fu < 0) continue;
                uint32_t au = __float_as_uint(cval[half][u]) & 0x7fffffffu;
                if (au > av || (au == av && fu < f)) ++rank;
            }
            if (rank < KSEL) {
                sel_val[(size_t)row * KSEL + rank] = cval[half][cid];
                sel_idx[(size_t)row * KSEL + rank] = f;
            }
        }
    }
}

// ================= decode: Wdec -> bf16 [F][D], one-pass gather ==============
__global__ __launch_bounds__(256) void transpose_wdec_bf16(
    const float* __restrict__ Wdec,   // [DIM][FDICT]
    ushort* __restrict__ WdecT)       // [FDICT][DIM] bf16
{
    __shared__ float t[64][65];
    const int f0 = blockIdx.x * 64;
    const int d0 = blockIdx.y * 64;
    const int tx = threadIdx.x & 63;
    const int ty = threadIdx.x >> 6;  // 0..3
#pragma unroll
    for (int r = 0; r < 16; ++r)
        t[ty * 16 + r][tx] = Wdec[(size_t)(d0 + ty * 16 + r) * FDICT + f0 + tx];
    __syncthreads();
#pragma unroll
    for (int r = 0; r < 16; ++r) {
        union { __bf16 h; ushort s; } cv;
        cv.h = (__bf16)t[tx][ty * 16 + r];
        WdecT[(size_t)(f0 + ty * 16 + r) * DIM + d0 + tx] = cv.s;
    }
}

__global__ __launch_bounds__(256) void decode_full_kernel(
    const ushort* __restrict__ WdecT,   // [FDICT][DIM] bf16
    const float* __restrict__ sel_val,
    const int* __restrict__ sel_idx,
    const float* __restrict__ bdec,
    float* __restrict__ out)
{
    const int row = blockIdx.x;
    const int tid = threadIdx.x;
    __shared__ float vv[KSEL];
    __shared__ int   ff[KSEL];
    if (tid < KSEL) {
        vv[tid] = sel_val[row * KSEL + tid];
        ff[tid] = sel_idx[row * KSEL + tid];
    }
    __syncthreads();
    const int d0 = tid * 8;
    float acc[8];
    {
        float4 b0 = *(const float4*)(bdec + d0);
        float4 b1 = *(const float4*)(bdec + d0 + 4);
        acc[0] = b0.x; acc[1] = b0.y; acc[2] = b0.z; acc[3] = b0.w;
        acc[4] = b1.x; acc[5] = b1.y; acc[6] = b1.z; acc[7] = b1.w;
    }
    for (int k = 0; k < KSEL; ++k) {
        const float v = vv[k];
        union { ushort s[8]; bf16x8 w; } u;
        u.w = *(const bf16x8*)(WdecT + (size_t)ff[k] * DIM + d0);
#pragma unroll
        for (int j = 0; j < 8; ++j)
            acc[j] = fmaf(v, bf16_to_f32(u.s[j]), acc[j]);
    }
    float* orow = out + (size_t)row * DIM + d0;
    float4 o0 = {acc[0], acc[1], acc[2], acc[3]};
    float4 o1 = {acc[4], acc[5], acc[6], acc[7]};
    *(float4*)(orow + 0) = o0;
    *(float4*)(orow + 4) = o1;
}

// ======================= launch =======================
extern "C" void kernel_launch(void* const* d_in, const int* in_sizes, int n_in,
                              void* d_out, int out_size, void* d_ws, size_t ws_size,
                              hipStream_t stream)
{
    const float* x    = (const float*)d_in[0];
    const float* Wenc = (const float*)d_in[1];
    const float* benc = (const float*)d_in[2];
    const float* Wdec = (const float*)d_in[3];
    const float* bdec = (const float*)d_in[4];
    (void)in_sizes; (void)n_in; (void)out_size; (void)ws_size;
    float* out = (float*)d_out;

    char* ws = (char*)d_ws;
    size_t off = 0;
    float*  cand_val = (float*)(ws + off);  off += (size_t)B_ROWS * CAP * 4;   // 12.6 MB
    int*    cand_idx = (int*)(ws + off);    off += (size_t)B_ROWS * CAP * 4;   // 12.6 MB
    int*    cand_cnt = (int*)(ws + off);    off += (size_t)B_ROWS * 4;
    float*  Tthr     = (float*)(ws + off);  off += (size_t)B_ROWS * 4;
    float*  wsum     = (float*)(ws + off);  off += 256;
    ushort* x_bf16   = (ushort*)(ws + off); off += (size_t)B_ROWS * DIM * 2;   // 8 MB
    int*    run_idx  = (int*)(ws + off);    off += (size_t)B_ROWS * TOPC * 4;
    float*  sel_val  = (float*)(ws + off);  off += (size_t)B_ROWS * KSEL * 4;
    int*    sel_idx  = (int*)(ws + off);    off += (size_t)B_ROWS * KSEL * 4;
    char*   big      = ws + off;            // 128 MB: wenc_bf16, then WdecT

    zero_kernel<<<(B_ROWS + 255) / 256, 256, 0, stream>>>(cand_cnt, wsum);
    wstat_kernel<<<8, 256, 0, stream>>>(Wenc, wsum);
    rownorm_kernel<<<B_ROWS, 256, 0, stream>>>(x, wsum, Tthr);
    conv_bf16_kernel<<<(B_ROWS * DIM) / (256 * 8), 256, 0, stream>>>(x, x_bf16);

    ushort* wenc_bf = (ushort*)big;
    conv_bf16_kernel<<<(int)(((size_t)FDICT * DIM) / (256 * 8)), 256, 0, stream>>>(
        Wenc, wenc_bf);
    enc_gemm_cand<<<(B_ROWS / GM) * (FDICT / GN), 256, 0, stream>>>(
        x_bf16, wenc_bf, benc, Tthr, cand_val, cand_idx, cand_cnt);

    select_kernel<<<B_ROWS, 256, 0, stream>>>(cand_val, cand_idx, cand_cnt, run_idx);
    refine_np_kernel<<<B_ROWS / 2, 256, 0, stream>>>(x, Wenc, benc, run_idx, sel_val, sel_idx);

    ushort* WdecT = (ushort*)big;   // reuse: encode phase done
    transpose_wdec_bf16<<<dim3(FDICT / 64, DIM / 64), 256, 0, stream>>>(Wdec, WdecT);
    decode_full_kernel<<<B_ROWS, 256, 0, stream>>>(WdecT, sel_val, sel_idx, bdec, out);
}

// Round 11
// 894.194 us; speedup vs baseline: 5.5123x; 1.0967x over previous
//
#include <hip/hip_runtime.h>
#include <stdint.h>

#define B_ROWS 2048
#define DIM    2048
#define FDICT  32768
#define KSEL   64
#define TOPC   96       // candidate list; refined bit-exactly vs np.einsum fp32
#define CAP    1536     // per-row candidate capacity (mean ~616 @ 2.35 sigma)
#define THRFAC 2.35f
#define WSAMPN (64 * DIM)   // Wenc sample count for sigma_w estimate

typedef __attribute__((ext_vector_type(8))) short bf16x8;
typedef __attribute__((ext_vector_type(4))) float f32x4;

__device__ __forceinline__ float bf16_to_f32(ushort u)
{
    return __uint_as_float(((uint32_t)u) << 16);
}

// ======================= init: zero counters =======================
__global__ __launch_bounds__(256) void zero_kernel(int* __restrict__ cand_cnt,
                                                   float* __restrict__ wsum)
{
    int i = blockIdx.x * 256 + threadIdx.x;
    if (i < B_ROWS) cand_cnt[i] = 0;
    if (i == 0) wsum[0] = 0.f;
}

// ======================= sigma_w estimate (sample 64 Wenc rows) ==============
__global__ __launch_bounds__(256) void wstat_kernel(
    const float* __restrict__ Wenc, float* __restrict__ wsum)
{
    __shared__ float red[256];
    const int tid = threadIdx.x;
    float s = 0.f;
    for (int i = blockIdx.x * 256 + tid; i < WSAMPN / 4; i += 8 * 256) {
        float4 w = ((const float4*)Wenc)[i];
        s += w.x * w.x + w.y * w.y + w.z * w.z + w.w * w.w;
    }
    red[tid] = s;
    __syncthreads();
    for (int o = 128; o > 0; o >>= 1) {
        if (tid < o) red[tid] += red[tid + o];
        __syncthreads();
    }
    if (tid == 0) atomicAdd(wsum, red[0]);
}

// ======================= per-row threshold: T = f * sigma_w * ||x_row|| ======
__global__ __launch_bounds__(256) void rownorm_kernel(
    const float* __restrict__ x, const float* __restrict__ wsum,
    float* __restrict__ T)
{
    __shared__ float red[256];
    const int row = blockIdx.x;
    const int tid = threadIdx.x;
    const float4* xr = (const float4*)(x + (size_t)row * DIM);
    float s = 0.f;
#pragma unroll
    for (int u = 0; u < 2; ++u) {
        float4 v = xr[tid + u * 256];
        s += v.x * v.x + v.y * v.y + v.z * v.z + v.w * v.w;
    }
    red[tid] = s;
    __syncthreads();
    for (int o = 128; o > 0; o >>= 1) {
        if (tid < o) red[tid] += red[tid + o];
        __syncthreads();
    }
    if (tid == 0)
        T[row] = THRFAC * sqrtf(wsum[0] / (float)WSAMPN) * sqrtf(red[0]);
}

// -------- fp32 -> bf16 (RNE) streaming convert --------
__global__ __launch_bounds__(256) void conv_bf16_kernel(
    const float* __restrict__ src, ushort* __restrict__ dst)
{
    const size_t i = ((size_t)blockIdx.x * 256 + threadIdx.x) * 8;
    float4 u = *(const float4*)(src + i);
    float4 v = *(const float4*)(src + i + 4);
    union { ushort s[8]; bf16x8 w; } o;
    float t[8] = {u.x, u.y, u.z, u.w, v.x, v.y, v.z, v.w};
#pragma unroll
    for (int j = 0; j < 8; ++j) {
        union { __bf16 h; ushort s; } cv;
        cv.h = (__bf16)t[j];
        o.s[j] = cv.s;
    }
    *(bf16x8*)(dst + i) = o.w;
}

// ====== encode GEMM: bf16 MFMA, 8 waves x (64x32 out) -> 32 AGPR/lane ->
// 4 waves/SIMD occupancy. GK=64 dbuf, T2 swizzle (r9-verified, 0 conflicts),
// T4 counted vmcnt, T1 XCD swizzle. Candidate emit by threshold.
#define GM 128
#define GN 128
#define GK 64
#define NT (DIM / GK)   // 32 K-tiles

__device__ __forceinline__ void gload_lds16(const void* g, void* l)
{
    __builtin_amdgcn_global_load_lds(
        (const __attribute__((address_space(1))) void*)(uintptr_t)g,
        (__attribute__((address_space(3))) void*)(uint32_t)(uintptr_t)l,
        16, 0, 0);
}

__global__ __launch_bounds__(512, 4) void enc_gemm_cand(
    const ushort* __restrict__ A,    // x_bf16    [B_ROWS][DIM]
    const ushort* __restrict__ Bw,   // Wenc_bf16 [FDICT][DIM]
    const float* __restrict__ benc,
    const float* __restrict__ T,     // [B_ROWS] per-row threshold
    float* __restrict__ cand_val,    // [B_ROWS][CAP]
    int* __restrict__ cand_idx,      // [B_ROWS][CAP]
    int* __restrict__ cand_cnt)      // [B_ROWS]
{
    __shared__ __align__(16) ushort As[2][GM * GK];   // 2 x 16 KB
    __shared__ __align__(16) ushort Bs[2][GN * GK];   // 2 x 16 KB

    const int tid  = threadIdx.x;
    const int lane = tid & 63;
    const int wv   = tid >> 6;            // 0..7
    const int wr   = wv >> 2, wc = wv & 3; // wave grid 2M x 4N: 64x32 out/wave
    const int lr   = lane & 15, lg = lane >> 4;

    // T1: bijective XCD-chunked swizzle. 4096 blocks, 8 XCDs -> 512 each.
    const int bid = blockIdx.x;
    const int nf  = (bid & 7) * 512 + (bid >> 3);
    const int row0 = (nf & 15) * GM;
    const int col0 = (nf >> 4) * GN;

    const ushort* aSrc = A  + (size_t)row0 * DIM;
    const ushort* bSrc = Bw + (size_t)col0 * DIM;

    const int srow   = (lane >> 3);                    // row within 8-row group
    const int scolsw = ((lane & 7) ^ srow) * 8;        // pre-swizzled source col

    f32x4 acc[4][2] = {};

    // Staging one K-tile (A 16KB + B 16KB): per wave 2 A ops + 2 B ops.
    // LDS written linearly; source col pre-swizzled (r9-verified layout).
#define STAGE(bsel, kt)                                                        \
    {                                                                          \
        const int k0_ = (kt) * GK;                                             \
        _Pragma("unroll")                                                      \
        for (int i_ = 0; i_ < 2; ++i_) {                                       \
            const int g_ = wv * 2 + i_;              /* 8-row group 0..15 */   \
            const int r_ = g_ * 8 + srow;                                      \
            gload_lds16(aSrc + (size_t)r_ * DIM + k0_ + scolsw,                \
                        (char*)&As[bsel][0] + g_ * 1024);                      \
            gload_lds16(bSrc + (size_t)r_ * DIM + k0_ + scolsw,                \
                        (char*)&Bs[bsel][0] + g_ * 1024);                      \
        }                                                                      \
    }

    STAGE(0, 0);
    int cur = 0;
    for (int kt = 0; kt < NT; ++kt) {
        // all waves finished ds_reads of buf cur^1 (previous iter) -> safe to
        // overwrite it with tile kt+1
        __builtin_amdgcn_s_barrier();
        if (kt + 1 < NT) {
            STAGE(cur ^ 1, kt + 1);
            // wait ONLY tile kt's 4 loads (oldest); kt+1's 4 stay in flight
            asm volatile("s_waitcnt vmcnt(4)" ::: "memory");
        } else {
            asm volatile("s_waitcnt vmcnt(0)" ::: "memory");
        }
        __builtin_amdgcn_s_barrier();        // tile kt resident for all waves
        __builtin_amdgcn_sched_barrier(0);

        bf16x8 af[2][4], bfr[2][2];
#pragma unroll
        for (int kk = 0; kk < 2; ++kk) {
            const int csw = (kk * 32 + lg * 8) ^ ((lr & 7) << 3);
#pragma unroll
            for (int mi = 0; mi < 4; ++mi) {
                const int R = wr * 64 + mi * 16 + lr;
                af[kk][mi] = *(const bf16x8*)(&As[cur][0] + R * GK + csw);
            }
#pragma unroll
            for (int ni = 0; ni < 2; ++ni) {
                const int R = wc * 32 + ni * 16 + lr;
                bfr[kk][ni] = *(const bf16x8*)(&Bs[cur][0] + R * GK + csw);
            }
        }
#pragma unroll
        for (int kk = 0; kk < 2; ++kk)
#pragma unroll
            for (int mi = 0; mi < 4; ++mi)
#pragma unroll
                for (int ni = 0; ni < 2; ++ni)
                    acc[mi][ni] = __builtin_amdgcn_mfma_f32_16x16x32_bf16(
                        af[kk][mi], bfr[kk][ni], acc[mi][ni], 0, 0, 0);
        cur ^= 1;
    }

    float bias[2];
#pragma unroll
    for (int ni = 0; ni < 2; ++ni)
        bias[ni] = benc[col0 + wc * 32 + ni * 16 + lr];

    // C/D layout (verified r4): col = lane&15, row = (lane>>4)*4 + reg
#pragma unroll
    for (int mi = 0; mi < 4; ++mi) {
#pragma unroll
        for (int r = 0; r < 4; ++r) {
            const int rloc = wr * 64 + mi * 16 + lg * 4 + r;
            const float t = T[row0 + rloc];
#pragma unroll
            for (int ni = 0; ni < 2; ++ni) {
                const float v = acc[mi][ni][r] + bias[ni];
                if (fabsf(v) >= t) {
                    const int grow = row0 + rloc;
                    const int gcol = col0 + wc * 32 + ni * 16 + lr;
                    int pos = atomicAdd(&cand_cnt[grow], 1);
                    if (pos < CAP) {
                        cand_val[(size_t)grow * CAP + pos] = v;
                        cand_idx[(size_t)grow * CAP + pos] = gcol;
                    }
                }
            }
        }
    }
#undef STAGE
}

// ============ exact radix select: candidates -> top-TOPC indices =============
__global__ __launch_bounds__(256) void select_kernel(
    const float* __restrict__ cand_val,
    const int* __restrict__ cand_idx,
    const int* __restrict__ cand_cnt,
    int* __restrict__ run_idx)
{
    const int row = blockIdx.x;
    const int tid = threadIdx.x;

    __shared__ uint32_t ua[CAP];
    __shared__ int      si[CAP];
    __shared__ int      hist[256];
    __shared__ uint32_t sh_prefix;
    __shared__ int      sh_cgt, c_out, c_eq;

    int cnt = cand_cnt[row];
    if (cnt > CAP) cnt = CAP;

    for (int j = tid; j < cnt; j += 256) {
        ua[j] = __float_as_uint(cand_val[(size_t)row * CAP + j]) & 0x7fffffffu;
        si[j] = cand_idx[(size_t)row * CAP + j];
    }
    if (tid == 0) { sh_prefix = 0u; sh_cgt = 0; c_out = 0; c_eq = 0; }
    __syncthreads();

    if (cnt <= TOPC) {
        if (tid < TOPC) run_idx[(size_t)row * TOPC + tid] = (tid < cnt) ? si[tid] : -1;
        return;
    }

    for (int p = 3; p >= 0; --p) {
        hist[tid] = 0;
        __syncthreads();
        const uint32_t mask = (p == 3) ? 0u : (0xffffffffu << ((p + 1) * 8));
        const uint32_t pref = sh_prefix;
        for (int j = tid; j < cnt; j += 256) {
            uint32_t u = ua[j];
            if ((u & mask) == pref)
                atomicAdd(&hist[(u >> (p * 8)) & 255], 1);
        }
        __syncthreads();
        if (tid == 0) {
            int cum = sh_cgt;
            int chosen = 0;
            for (int b = 255; b >= 0; --b) {
                int c = hist[b];
                if (cum + c >= TOPC) { chosen = b; break; }
                cum += c;
            }
            sh_prefix = sh_prefix | ((uint32_t)chosen << (p * 8));
            sh_cgt = cum;
        }
        __syncthreads();
    }

    const uint32_t uth = sh_prefix;
    for (int j = tid; j < cnt; j += 256) {
        if (ua[j] > uth) {
            int pos = atomicAdd(&c_out, 1);
            run_idx[(size_t)row * TOPC + pos] = si[j];
        }
    }
    __syncthreads();
    const int base = c_out;
    for (int j = tid; j < cnt; j += 256) {
        if (ua[j] == uth) {
            int e = atomicAdd(&c_eq, 1);
            int slot = base + e;
            if (slot < TOPC) run_idx[(size_t)row * TOPC + slot] = si[j];
        }
    }
}

// ============ np.einsum-bit-exact refinement of TOPC candidates ==============
// numpy fp32 SSE chain: 4 accumulators over d%4 ascending, round(mul) then
// round(add) (no FMA), combined (a0+a2)+(a1+a3), then + b_enc.
// Ping-pong double-buffered loads (2x8 float4 in flight) for MLP.
__global__ __launch_bounds__(256) void refine_np_kernel(
    const float* __restrict__ x,
    const float* __restrict__ Wenc,
    const float* __restrict__ benc,
    const int* __restrict__ run_idx,
    float* __restrict__ sel_val,
    int* __restrict__ sel_idx)
{
    const int half = threadIdx.x >> 7;      // row within block (0..1)
    const int cid  = threadIdx.x & 127;     // candidate id (<TOPC active)
    const int row  = blockIdx.x * 2 + half;

    __shared__ __align__(16) float xs[2][DIM];
    __shared__ float cval[2][TOPC];
    __shared__ int   cidx[2][TOPC];

    {
        const float4* src = (const float4*)(x + (size_t)blockIdx.x * 2 * DIM);
        for (int i = threadIdx.x; i < 2 * DIM / 4; i += 256)
            ((float4*)xs)[i] = src[i];
    }
    if (cid < TOPC) cidx[half][cid] = run_idx[(size_t)row * TOPC + cid];
    __syncthreads();

    if (cid < TOPC) {
        const int f = cidx[half][cid];
        if (f >= 0) {
            const float4* w4 = (const float4*)(Wenc + (size_t)f * DIM);
            const float4* x4 = (const float4*)xs[half];
            float a0 = 0.f, a1 = 0.f, a2 = 0.f, a3 = 0.f;
            float4 pa[8], pb[8];
#pragma unroll
            for (int u = 0; u < 8; ++u) pa[u] = w4[u];
            for (int t0 = 0; t0 < DIM / 4; t0 += 16) {
#pragma unroll
                for (int u = 0; u < 8; ++u) pb[u] = w4[t0 + 8 + u];
#pragma unroll
                for (int u = 0; u < 8; ++u) {
                    float4 xv = x4[t0 + u];
                    a0 = __fadd_rn(a0, __fmul_rn(xv.x, pa[u].x));
                    a1 = __fadd_rn(a1, __fmul_rn(xv.y, pa[u].y));
                    a2 = __fadd_rn(a2, __fmul_rn(xv.z, pa[u].z));
                    a3 = __fadd_rn(a3, __fmul_rn(xv.w, pa[u].w));
                }
                if (t0 + 16 < DIM / 4) {
#pragma unroll
                    for (int u = 0; u < 8; ++u) pa[u] = w4[t0 + 16 + u];
                }
#pragma unroll
                for (int u = 0; u < 8; ++u) {
                    float4 xv = x4[t0 + 8 + u];
                    a0 = __fadd_rn(a0, __fmul_rn(xv.x, pb[u].x));
                    a1 = __fadd_rn(a1, __fmul_rn(xv.y, pb[u].y));
                    a2 = __fadd_rn(a2, __fmul_rn(xv.z, pb[u].z));
                    a3 = __fadd_rn(a3, __fmul_rn(xv.w, pb[u].w));
                }
            }
            float v = __fadd_rn(__fadd_rn(a0, a2), __fadd_rn(a1, a3));
            cval[half][cid] = __fadd_rn(v, benc[f]);
        } else {
            cval[half][cid] = 0.f;
        }
    }
    __syncthreads();

    if (cid < TOPC) {
        const int f = cidx[half][cid];
        if (f >= 0) {
            const uint32_t av = __float_as_uint(cval[half][cid]) & 0x7fffffffu;
            int rank = 0;
            for (int u = 0; u < TOPC; ++u) {
                if (u == cid) continue;
                int fu = cidx[half][u];
                if (fu < 0) continue;
                uint32_t au = __float_as_uint(cval[half][u]) & 0x7fffffffu;
                if (au > av || (au == av && fu < f)) ++rank;
            }
            if (rank < KSEL) {
                sel_val[(size_t)row * KSEL + rank] = cval[half][cid];
                sel_idx[(size_t)row * KSEL + rank] = f;
            }
        }
    }
}

// ================= decode: Wdec -> bf16 [F][D], one-pass gather ==============
__global__ __launch_bounds__(256) void transpose_wdec_bf16(
    const float* __restrict__ Wdec,   // [DIM][FDICT]
    ushort* __restrict__ WdecT)       // [FDICT][DIM] bf16
{
    __shared__ float t[64][65];
    const int f0 = blockIdx.x * 64;
    const int d0 = blockIdx.y * 64;
    const int tx = threadIdx.x & 63;
    const int ty = threadIdx.x >> 6;  // 0..3
#pragma unroll
    for (int r = 0; r < 16; ++r)
        t[ty * 16 + r][tx] = Wdec[(size_t)(d0 + ty * 16 + r) * FDICT + f0 + tx];
    __syncthreads();
#pragma unroll
    for (int r = 0; r < 16; ++r) {
        union { __bf16 h; ushort s; } cv;
        cv.h = (__bf16)t[tx][ty * 16 + r];
        WdecT[(size_t)(f0 + ty * 16 + r) * DIM + d0 + tx] = cv.s;
    }
}

__global__ __launch_bounds__(256) void decode_full_kernel(
    const ushort* __restrict__ WdecT,   // [FDICT][DIM] bf16
    const float* __restrict__ sel_val,
    const int* __restrict__ sel_idx,
    const float* __restrict__ bdec,
    float* __restrict__ out)
{
    const int row = blockIdx.x;
    const int tid = threadIdx.x;
    __shared__ float vv[KSEL];
    __shared__ int   ff[KSEL];
    if (tid < KSEL) {
        vv[tid] = sel_val[row * KSEL + tid];
        ff[tid] = sel_idx[row * KSEL + tid];
    }
    __syncthreads();
    const int d0 = tid * 8;
    float acc[8];
    {
        float4 b0 = *(const float4*)(bdec + d0);
        float4 b1 = *(const float4*)(bdec + d0 + 4);
        acc[0] = b0.x; acc[1] = b0.y; acc[2] = b0.z; acc[3] = b0.w;
        acc[4] = b1.x; acc[5] = b1.y; acc[6] = b1.z; acc[7] = b1.w;
    }
    for (int k = 0; k < KSEL; ++k) {
        const float v = vv[k];
        union { ushort s[8]; bf16x8 w; } u;
        u.w = *(const bf16x8*)(WdecT + (size_t)ff[k] * DIM + d0);
#pragma unroll
        for (int j = 0; j < 8; ++j)
            acc[j] = fmaf(v, bf16_to_f32(u.s[j]), acc[j]);
    }
    float* orow = out + (size_t)row * DIM + d0;
    float4 o0 = {acc[0], acc[1], acc[2], acc[3]};
    float4 o1 = {acc[4], acc[5], acc[6], acc[7]};
    *(float4*)(orow + 0) = o0;
    *(float4*)(orow + 4) = o1;
}

// ======================= launch =======================
extern "C" void kernel_launch(void* const* d_in, const int* in_sizes, int n_in,
                              void* d_out, int out_size, void* d_ws, size_t ws_size,
                              hipStream_t stream)
{
    const float* x    = (const float*)d_in[0];
    const float* Wenc = (const float*)d_in[1];
    const float* benc = (const float*)d_in[2];
    const float* Wdec = (const float*)d_in[3];
    const float* bdec = (const float*)d_in[4];
    (void)in_sizes; (void)n_in; (void)out_size; (void)ws_size;
    float* out = (float*)d_out;

    char* ws = (char*)d_ws;
    size_t off = 0;
    float*  cand_val = (float*)(ws + off);  off += (size_t)B_ROWS * CAP * 4;   // 12.6 MB
    int*    cand_idx = (int*)(ws + off);    off += (size_t)B_ROWS * CAP * 4;   // 12.6 MB
    int*    cand_cnt = (int*)(ws + off);    off += (size_t)B_ROWS * 4;
    float*  Tthr     = (float*)(ws + off);  off += (size_t)B_ROWS * 4;
    float*  wsum     = (float*)(ws + off);  off += 256;
    ushort* x_bf16   = (ushort*)(ws + off); off += (size_t)B_ROWS * DIM * 2;   // 8 MB
    int*    run_idx  = (int*)(ws + off);    off += (size_t)B_ROWS * TOPC * 4;
    float*  sel_val  = (float*)(ws + off);  off += (size_t)B_ROWS * KSEL * 4;
    int*    sel_idx  = (int*)(ws + off);    off += (size_t)B_ROWS * KSEL * 4;
    char*   big      = ws + off;            // 128 MB: wenc_bf16, then WdecT

    zero_kernel<<<(B_ROWS + 255) / 256, 256, 0, stream>>>(cand_cnt, wsum);
    wstat_kernel<<<8, 256, 0, stream>>>(Wenc, wsum);
    rownorm_kernel<<<B_ROWS, 256, 0, stream>>>(x, wsum, Tthr);
    conv_bf16_kernel<<<(B_ROWS * DIM) / (256 * 8), 256, 0, stream>>>(x, x_bf16);

    ushort* wenc_bf = (ushort*)big;
    conv_bf16_kernel<<<(int)(((size_t)FDICT * DIM) / (256 * 8)), 256, 0, stream>>>(
        Wenc, wenc_bf);
    enc_gemm_cand<<<(B_ROWS / GM) * (FDICT / GN), 512, 0, stream>>>(
        x_bf16, wenc_bf, benc, Tthr, cand_val, cand_idx, cand_cnt);

    select_kernel<<<B_ROWS, 256, 0, stream>>>(cand_val, cand_idx, cand_cnt, run_idx);
    refine_np_kernel<<<B_ROWS / 2, 256, 0, stream>>>(x, Wenc, benc, run_idx, sel_val, sel_idx);

    ushort* WdecT = (ushort*)big;   // reuse: encode phase done
    transpose_wdec_bf16<<<dim3(FDICT / 64, DIM / 64), 256, 0, stream>>>(Wdec, WdecT);
    decode_full_kernel<<<B_ROWS, 256, 0, stream>>>(WdecT, sel_val, sel_idx, bdec, out);
}